// Round 1
// baseline (796.561 us; speedup 1.0000x reference)
//
#include <hip/hip_runtime.h>
#include <cstddef>

#define N_TOK 2048
#define BATCH 2
#define EMB   1024
#define NH    16
#define HD    64
#define NP    16
#define BHN   32
#define CHK   128
#define NCHK  16
#define SCALING 0.125f

// ---------------- pq projection: pq_s[bh][p][d] = (pquery @ Wpq^T + bpq) * scaling ----------------
__global__ __launch_bounds__(256) void pq_proj_kernel(
    const float* __restrict__ pquery, const float* __restrict__ Wpq,
    const float* __restrict__ bpq, float* __restrict__ pq_s)
{
  const int r = blockIdx.x;          // 0..31 : r = p*BATCH + ib  (pquery is (P,b,E))
  const int p = r >> 1, ib = r & 1;
  const int t = threadIdx.x;
  __shared__ float xs[EMB];
  for (int l = t; l < EMB; l += 256) xs[l] = pquery[(size_t)r * EMB + l];
  __syncthreads();
  for (int eo = 0; eo < 4; ++eo) {
    const int e = t + eo * 256;
    const float* wrow = &Wpq[(size_t)e * EMB];
    float acc = 0.f;
    for (int cc = 0; cc < EMB; cc += 4) {
      const float4 w4 = *(const float4*)&wrow[cc];
      acc += xs[cc] * w4.x + xs[cc + 1] * w4.y + xs[cc + 2] * w4.z + xs[cc + 3] * w4.w;
    }
    acc = (acc + bpq[e]) * SCALING;
    const int h = e >> 6, d = e & 63;
    const int bh = ib * NH + h;
    pq_s[((size_t)bh * NP + p) * HD + d] = acc;
  }
}

// ---------------- generic NT GEMM: Y(MxN) = X(MxK) @ W(NxK)^T + bias ----------------
// BM=128, BN=64, BK=16, per-thread 8x4
__global__ __launch_bounds__(256) void gemm_nt_kernel(
    const float* __restrict__ X, const float* __restrict__ W,
    const float* __restrict__ bias, float* __restrict__ Y,
    int M, int N, int K)
{
  __shared__ float As[16][132];
  __shared__ float Bs[16][68];
  const int t = threadIdx.x;
  const int m0 = blockIdx.y * 128, n0 = blockIdx.x * 64;
  const int ty = t >> 4, tx = t & 15;
  float acc[8][4] = {{0.f}};
  for (int k0 = 0; k0 < K; k0 += 16) {
    #pragma unroll
    for (int u = 0; u < 2; ++u) {
      const int l = t + 256 * u;              // 0..511 -> 512 float4 = 128x16
      const int i = l >> 2, j = (l & 3) << 2;
      const float4 a4 = *(const float4*)&X[(size_t)(m0 + i) * K + k0 + j];
      As[j][i] = a4.x; As[j + 1][i] = a4.y; As[j + 2][i] = a4.z; As[j + 3][i] = a4.w;
    }
    {
      const int i = t >> 2, j = (t & 3) << 2; // 256 float4 = 64x16
      const float4 b4 = *(const float4*)&W[(size_t)(n0 + i) * K + k0 + j];
      Bs[j][i] = b4.x; Bs[j + 1][i] = b4.y; Bs[j + 2][i] = b4.z; Bs[j + 3][i] = b4.w;
    }
    __syncthreads();
    #pragma unroll
    for (int kk = 0; kk < 16; ++kk) {
      float af[8], bf[4];
      #pragma unroll
      for (int ii = 0; ii < 8; ++ii) af[ii] = As[kk][ty * 8 + ii];
      #pragma unroll
      for (int jj = 0; jj < 4; ++jj) bf[jj] = Bs[kk][tx * 4 + jj];
      #pragma unroll
      for (int ii = 0; ii < 8; ++ii)
        #pragma unroll
        for (int jj = 0; jj < 4; ++jj) acc[ii][jj] += af[ii] * bf[jj];
    }
    __syncthreads();
  }
  #pragma unroll
  for (int ii = 0; ii < 8; ++ii) {
    const int m = m0 + ty * 8 + ii, nb = n0 + tx * 4;
    float4 r;
    r.x = acc[ii][0] + bias[nb];     r.y = acc[ii][1] + bias[nb + 1];
    r.z = acc[ii][2] + bias[nb + 2]; r.w = acc[ii][3] + bias[nb + 3];
    *(float4*)&Y[(size_t)m * N + nb] = r;
  }
}

// ---------------- pattn[bh][i][p] = sum_d query[i,ib,h*64+d] * pq_s[bh][p][d] ----------------
__global__ __launch_bounds__(256) void pattn_kernel(
    const float* __restrict__ query, const float* __restrict__ pq_s, float* __restrict__ pe)
{
  const int c = blockIdx.x, bh = blockIdx.y;
  const int ib = bh >> 4, h = bh & 15;
  const int t = threadIdx.x;
  const int i0 = c * CHK;
  __shared__ float qs[CHK][68];
  __shared__ float ps[NP][68];
  for (int l = t; l < 2048; l += 256) {
    const int i = l >> 4, d4 = (l & 15) << 2;
    *(float4*)&qs[i][d4] =
        *(const float4*)&query[((size_t)(i0 + i) * BATCH + ib) * EMB + h * HD + d4];
  }
  {
    const int pp = t >> 4, d4 = (t & 15) << 2;   // 256 threads = 256 float4 = 16x64
    *(float4*)&ps[pp][d4] = *(const float4*)&pq_s[((size_t)bh * NP + pp) * HD + d4];
  }
  __syncthreads();
  const int p = t & 15, ig = t >> 4;
  for (int rep = 0; rep < 8; ++rep) {
    const int i = rep * 16 + ig;
    float acc = 0.f;
    for (int d = 0; d < HD; ++d) acc += qs[i][d] * ps[p][d];
    pe[(size_t)bh * (N_TOK * NP) + (size_t)(i0 + i) * NP + p] = acc;
  }
}

// ---------------- per-(bh,p) column max over n, then pe <- exp(pe - max) ----------------
__global__ __launch_bounds__(256) void colmax_exp_kernel(float* __restrict__ pe)
{
  const int bh = blockIdx.x;
  const int t = threadIdx.x;
  __shared__ float red[16][17];
  __shared__ float ms[16];
  const int p = t & 15, g = t >> 4;
  const size_t base = (size_t)bh * (N_TOK * NP);
  float mx = -3.0e38f;
  for (int i = g * 128; i < g * 128 + 128; ++i)
    mx = fmaxf(mx, pe[base + (size_t)i * NP + p]);
  red[g][p] = mx;
  __syncthreads();
  if (t < 16) {
    float m2 = red[0][t];
    for (int g2 = 1; g2 < 16; ++g2) m2 = fmaxf(m2, red[g2][t]);
    ms[t] = m2;
  }
  __syncthreads();
  for (int l = t; l < N_TOK * NP; l += 256)
    pe[base + l] = expf(pe[base + l] - ms[l & 15]);
}

// ---------------- per-chunk totals: Tk[bh][c][d][p], Tv[bh][c][p][d], Ts[bh][c][p] ----------------
__global__ __launch_bounds__(256) void chunk_totals_kernel(
    const float* __restrict__ pe, const float* __restrict__ Kbuf,
    const float* __restrict__ Vbuf, float* __restrict__ Tk,
    float* __restrict__ Tv, float* __restrict__ Ts)
{
  const int c = blockIdx.x, bh = blockIdx.y;
  const int ib = bh >> 4, h = bh & 15;
  const int t = threadIdx.x;
  const int i0 = c * CHK;
  __shared__ float Es[CHK][16];
  __shared__ float kv[CHK][68];
  for (int l = t; l < 2048; l += 256)
    Es[l >> 4][l & 15] = pe[(size_t)bh * (N_TOK * NP) + (size_t)i0 * NP + l];
  for (int l = t; l < 2048; l += 256) {
    const int i = l >> 4, d4 = (l & 15) << 2;
    *(float4*)&kv[i][d4] =
        *(const float4*)&Kbuf[((size_t)(i0 + i) * BATCH + ib) * EMB + h * HD + d4];
  }
  __syncthreads();
  {
    const int p = t & 15, d0 = (t >> 4) * 4;
    float a0 = 0, a1 = 0, a2 = 0, a3 = 0;
    for (int j = 0; j < CHK; ++j) {
      const float e = Es[j][p];
      a0 += kv[j][d0] * e; a1 += kv[j][d0 + 1] * e;
      a2 += kv[j][d0 + 2] * e; a3 += kv[j][d0 + 3] * e;
    }
    const size_t tb = (size_t)(bh * NCHK + c) * 1024;
    Tk[tb + (d0 + 0) * 16 + p] = a0; Tk[tb + (d0 + 1) * 16 + p] = a1;
    Tk[tb + (d0 + 2) * 16 + p] = a2; Tk[tb + (d0 + 3) * 16 + p] = a3;
  }
  __syncthreads();
  for (int l = t; l < 2048; l += 256) {
    const int i = l >> 4, d4 = (l & 15) << 2;
    *(float4*)&kv[i][d4] =
        *(const float4*)&Vbuf[((size_t)(i0 + i) * BATCH + ib) * EMB + h * HD + d4];
  }
  __syncthreads();
  {
    const int p = t >> 4, d0 = (t & 15) * 4;
    float a0 = 0, a1 = 0, a2 = 0, a3 = 0;
    for (int j = 0; j < CHK; ++j) {
      const float e = Es[j][p];
      a0 += kv[j][d0] * e; a1 += kv[j][d0 + 1] * e;
      a2 += kv[j][d0 + 2] * e; a3 += kv[j][d0 + 3] * e;
    }
    const size_t tb = (size_t)(bh * NCHK + c) * 1024;
    float4 r; r.x = a0; r.y = a1; r.z = a2; r.w = a3;
    *(float4*)&Tv[tb + p * 64 + d0] = r;
  }
  if (t < 16) {
    float s = 0.f;
    for (int j = 0; j < CHK; ++j) s += Es[j][t];
    Ts[(size_t)(bh * NCHK + c) * 16 + t] = s;
  }
}

// ---------------- exclusive scan over chunks (in place) ----------------
__global__ __launch_bounds__(256) void chunk_scan_kernel(
    float* __restrict__ Tk, float* __restrict__ Tv, float* __restrict__ Ts)
{
  const int bh = blockIdx.x, t = threadIdx.x;
  for (int e = t; e < 1024; e += 256) {
    const size_t base = (size_t)bh * (NCHK * 1024) + e;
    float run = 0.f;
    for (int c = 0; c < NCHK; ++c) { const float v = Tk[base + c * 1024]; Tk[base + c * 1024] = run; run += v; }
    run = 0.f;
    for (int c = 0; c < NCHK; ++c) { const float v = Tv[base + c * 1024]; Tv[base + c * 1024] = run; run += v; }
  }
  if (t < 16) {
    const size_t base = (size_t)bh * (NCHK * 16) + t;
    float run = 0.f;
    for (int c = 0; c < NCHK; ++c) { const float v = Ts[base + c * 16]; Ts[base + c * 16] = run; run += v; }
  }
}

// ---------------- within-chunk causal attention (both stages) ----------------
__global__ __launch_bounds__(256) void chunk_attn_kernel(
    const float* __restrict__ query, const float* __restrict__ Kbuf,
    const float* __restrict__ Vbuf, const float* __restrict__ pe,
    const float* __restrict__ Tk, const float* __restrict__ Tv,
    const float* __restrict__ Ts, float* __restrict__ aw_buf,
    float* __restrict__ outpre)
{
  const int c = blockIdx.x, bh = blockIdx.y;
  const int ib = bh >> 4, h = bh & 15;
  const int t = threadIdx.x;
  const int i0 = c * CHK;

  __shared__ float Qs[CHK][65];   // scaled q
  __shared__ float Ks[CHK][65];   // k, later reused for v
  __shared__ float Es[CHK][16];
  __shared__ float As[CHK][33];   // A / B sub-tile (128 x 32)
  __shared__ float Nb[HD][16];
  __shared__ float Mb[16][68];
  __shared__ float Sb[16];
  __shared__ float gs[CHK][17];

  for (int l = t; l < 2048; l += 256) {
    const int i = l >> 4, d4 = (l & 15) << 2;
    const size_t gidx = ((size_t)(i0 + i) * BATCH + ib) * EMB + h * HD + d4;
    const float4 q4 = *(const float4*)&query[gidx];
    Qs[i][d4] = q4.x * SCALING; Qs[i][d4 + 1] = q4.y * SCALING;
    Qs[i][d4 + 2] = q4.z * SCALING; Qs[i][d4 + 3] = q4.w * SCALING;
    const float4 k4 = *(const float4*)&Kbuf[gidx];
    Ks[i][d4] = k4.x; Ks[i][d4 + 1] = k4.y; Ks[i][d4 + 2] = k4.z; Ks[i][d4 + 3] = k4.w;
  }
  for (int l = t; l < 2048; l += 256)
    Es[l >> 4][l & 15] = pe[(size_t)bh * (N_TOK * NP) + (size_t)i0 * NP + l];
  for (int l = t; l < 1024; l += 256)
    Nb[l >> 4][l & 15] = Tk[(size_t)(bh * NCHK + c) * 1024 + l];
  for (int l = t; l < 1024; l += 256)
    Mb[l >> 6][l & 63] = Tv[(size_t)(bh * NCHK + c) * 1024 + l];
  if (t < 16) Sb[t] = Ts[(size_t)(bh * NCHK + c) * 16 + t];
  __syncthreads();

  const int p = t & 15, ig = t >> 4;     // stage owner: (i = rep*16+ig, p)
  const int r = t & 31, cb = t >> 5;     // tile-compute owner

  // ---- stage 1: W1[i,p] = q_i . Nb[:,p] + sum_{j<i} (q_i.k_j) Es[j,p];  S = Sb + prefix(Es)
  float W1[8], Sc[8];
  #pragma unroll
  for (int rep = 0; rep < 8; ++rep) {
    const int i = rep * 16 + ig;
    float acc = 0.f;
    for (int d = 0; d < HD; ++d) acc += Qs[i][d] * Nb[d][p];
    W1[rep] = acc;
    Sc[rep] = Sb[p];
  }

  for (int jb = 0; jb < 4; ++jb) {
    {  // A sub-tile: rows r+32*ii, cols cb+8*q  (jj local in [0,32))
      float a00=0,a01=0,a02=0,a03=0, a10=0,a11=0,a12=0,a13=0;
      float a20=0,a21=0,a22=0,a23=0, a30=0,a31=0,a32=0,a33=0;
      const int jr = jb * 32 + cb;
      for (int d = 0; d < HD; ++d) {
        const float q0 = Qs[r][d], q1 = Qs[r + 32][d], q2 = Qs[r + 64][d], q3 = Qs[r + 96][d];
        const float k0 = Ks[jr][d], k1 = Ks[jr + 8][d], k2 = Ks[jr + 16][d], k3 = Ks[jr + 24][d];
        a00 += q0*k0; a01 += q0*k1; a02 += q0*k2; a03 += q0*k3;
        a10 += q1*k0; a11 += q1*k1; a12 += q1*k2; a13 += q1*k3;
        a20 += q2*k0; a21 += q2*k1; a22 += q2*k2; a23 += q2*k3;
        a30 += q3*k0; a31 += q3*k1; a32 += q3*k2; a33 += q3*k3;
      }
      As[r     ][cb]      = a00; As[r     ][cb + 8]  = a01; As[r     ][cb + 16] = a02; As[r     ][cb + 24] = a03;
      As[r + 32][cb]      = a10; As[r + 32][cb + 8]  = a11; As[r + 32][cb + 16] = a12; As[r + 32][cb + 24] = a13;
      As[r + 64][cb]      = a20; As[r + 64][cb + 8]  = a21; As[r + 64][cb + 16] = a22; As[r + 64][cb + 24] = a23;
      As[r + 96][cb]      = a30; As[r + 96][cb + 8]  = a31; As[r + 96][cb + 16] = a32; As[r + 96][cb + 24] = a33;
    }
    __syncthreads();
    const int j0 = jb * 32;
    for (int jj = 0; jj < 32; ++jj) {
      const int j = j0 + jj;
      const float e = Es[j][p];
      #pragma unroll
      for (int rep = 0; rep < 8; ++rep) {
        const int i = rep * 16 + ig;
        if (i > j) { W1[rep] += As[i][jj] * e; Sc[rep] += e; }
      }
    }
    __syncthreads();
  }

  // ---- finalize stage 1: divide, softmax over p (16-lane group), g = aw / ssafe
  #pragma unroll
  for (int rep = 0; rep < 8; ++rep) {
    const int i = rep * 16 + ig;
    const float s = Sc[rep];
    const float ssafe = (s > 0.f) ? s : 1.f;
    const float w = W1[rep] / ssafe;
    float m = w;
    #pragma unroll
    for (int off = 1; off < 16; off <<= 1) m = fmaxf(m, __shfl_xor(m, off, 64));
    const float e = expf(w - m);
    float ss = e;
    #pragma unroll
    for (int off = 1; off < 16; off <<= 1) ss += __shfl_xor(ss, off, 64);
    const float aw = e / ss;
    aw_buf[(size_t)bh * (N_TOK * NP) + (size_t)(i0 + i) * NP + p] = aw;
    gs[i][p] = aw / ssafe;
  }
  __syncthreads();

  // ---- reload V into Ks
  for (int l = t; l < 2048; l += 256) {
    const int i = l >> 4, d4 = (l & 15) << 2;
    const float4 v4 =
        *(const float4*)&Vbuf[((size_t)(i0 + i) * BATCH + ib) * EMB + h * HD + d4];
    Ks[i][d4] = v4.x; Ks[i][d4 + 1] = v4.y; Ks[i][d4 + 2] = v4.z; Ks[i][d4 + 3] = v4.w;
  }
  __syncthreads();

  // ---- stage 2: out[i,d] = g_i . Mb[:,d] + sum_{j<i} (g_i . Es[j,:]) v[j,d]
  const int db = (t & 15) * 4;
  float o[8][4] = {{0.f}};
  for (int jb = 0; jb < 4; ++jb) {
    {  // B sub-tile: B[i][jj] = sum_p gs[i][p] * Es[j][p]
      float a00=0,a01=0,a02=0,a03=0, a10=0,a11=0,a12=0,a13=0;
      float a20=0,a21=0,a22=0,a23=0, a30=0,a31=0,a32=0,a33=0;
      const int jr = jb * 32 + cb;
      for (int pp = 0; pp < 16; ++pp) {
        const float g0 = gs[r][pp], g1 = gs[r + 32][pp], g2 = gs[r + 64][pp], g3 = gs[r + 96][pp];
        const float e0 = Es[jr][pp], e1 = Es[jr + 8][pp], e2 = Es[jr + 16][pp], e3 = Es[jr + 24][pp];
        a00 += g0*e0; a01 += g0*e1; a02 += g0*e2; a03 += g0*e3;
        a10 += g1*e0; a11 += g1*e1; a12 += g1*e2; a13 += g1*e3;
        a20 += g2*e0; a21 += g2*e1; a22 += g2*e2; a23 += g2*e3;
        a30 += g3*e0; a31 += g3*e1; a32 += g3*e2; a33 += g3*e3;
      }
      As[r     ][cb]      = a00; As[r     ][cb + 8]  = a01; As[r     ][cb + 16] = a02; As[r     ][cb + 24] = a03;
      As[r + 32][cb]      = a10; As[r + 32][cb + 8]  = a11; As[r + 32][cb + 16] = a12; As[r + 32][cb + 24] = a13;
      As[r + 64][cb]      = a20; As[r + 64][cb + 8]  = a21; As[r + 64][cb + 16] = a22; As[r + 64][cb + 24] = a23;
      As[r + 96][cb]      = a30; As[r + 96][cb + 8]  = a31; As[r + 96][cb + 16] = a32; As[r + 96][cb + 24] = a33;
    }
    __syncthreads();
    const int j0 = jb * 32;
    for (int jj = 0; jj < 32; ++jj) {
      const int j = j0 + jj;
      const float k0 = Ks[j][db], k1 = Ks[j][db + 1], k2 = Ks[j][db + 2], k3 = Ks[j][db + 3];
      #pragma unroll
      for (int rep = 0; rep < 8; ++rep) {
        const int i = rep * 16 + ig;
        if (i > j) {
          const float bb = As[i][jj];
          o[rep][0] += bb * k0; o[rep][1] += bb * k1;
          o[rep][2] += bb * k2; o[rep][3] += bb * k3;
        }
      }
    }
    __syncthreads();
  }

  // ---- Mb term + write outpre (same (n,b,E) layout as query)
  #pragma unroll
  for (int rep = 0; rep < 8; ++rep) {
    const int i = rep * 16 + ig;
    float o0 = o[rep][0], o1 = o[rep][1], o2 = o[rep][2], o3 = o[rep][3];
    for (int pp = 0; pp < 16; ++pp) {
      const float gg = gs[i][pp];
      o0 += gg * Mb[pp][db]; o1 += gg * Mb[pp][db + 1];
      o2 += gg * Mb[pp][db + 2]; o3 += gg * Mb[pp][db + 3];
    }
    float4 rr; rr.x = o0; rr.y = o1; rr.z = o2; rr.w = o3;
    *(float4*)&outpre[((size_t)(i0 + i) * BATCH + ib) * EMB + h * HD + db] = rr;
  }
}

// ---------------- aw mean over heads ----------------
__global__ __launch_bounds__(256) void aw_avg_kernel(
    const float* __restrict__ aw_buf, float* __restrict__ out_aw)
{
  const int idx = blockIdx.x * 256 + threadIdx.x;   // 2*2048*16 = 65536
  const int p = idx & 15;
  const int i = (idx >> 4) & 2047;
  const int ib = idx >> 15;
  float s = 0.f;
  for (int hh = 0; hh < NH; ++hh)
    s += aw_buf[((size_t)(ib * NH + hh) * N_TOK + i) * NP + p];
  out_aw[idx] = s * (1.f / 16.f);
}

extern "C" void kernel_launch(void* const* d_in, const int* in_sizes, int n_in,
                              void* d_out, int out_size, void* d_ws, size_t ws_size,
                              hipStream_t stream) {
  const float* query  = (const float*)d_in[0];
  const float* pquery = (const float*)d_in[1];
  const float* Wpq    = (const float*)d_in[2];
  const float* bpq    = (const float*)d_in[3];
  const float* Wk     = (const float*)d_in[4];
  const float* bk     = (const float*)d_in[5];
  const float* Wv     = (const float*)d_in[6];
  const float* bv     = (const float*)d_in[7];
  const float* Wo     = (const float*)d_in[8];
  const float* bo     = (const float*)d_in[9];
  float* out = (float*)d_out;
  float* ws  = (float*)d_ws;

  float* pq_s   = ws;                    // 32*16*64          = 32768
  float* pe     = pq_s   + 32768;        // 32*2048*16        = 1048576
  float* Kbuf   = pe     + 1048576;      // 4096*1024         = 4194304
  float* Vbuf   = Kbuf   + 4194304;      // 4194304
  float* aw_buf = Vbuf   + 4194304;      // 1048576
  float* outpre = aw_buf + 1048576;      // 4194304
  float* Tk     = outpre + 4194304;      // 32*16*1024        = 524288
  float* Tv     = Tk     + 524288;       // 524288
  float* Ts     = Tv     + 524288;       // 32*16*16          = 8192

  pq_proj_kernel<<<32, 256, 0, stream>>>(pquery, Wpq, bpq, pq_s);
  gemm_nt_kernel<<<dim3(16, 32), 256, 0, stream>>>(query, Wk, bk, Kbuf, 4096, 1024, 1024);
  gemm_nt_kernel<<<dim3(16, 32), 256, 0, stream>>>(query, Wv, bv, Vbuf, 4096, 1024, 1024);
  pattn_kernel<<<dim3(NCHK, BHN), 256, 0, stream>>>(query, pq_s, pe);
  colmax_exp_kernel<<<BHN, 256, 0, stream>>>(pe);
  chunk_totals_kernel<<<dim3(NCHK, BHN), 256, 0, stream>>>(pe, Kbuf, Vbuf, Tk, Tv, Ts);
  chunk_scan_kernel<<<BHN, 256, 0, stream>>>(Tk, Tv, Ts);
  chunk_attn_kernel<<<dim3(NCHK, BHN), 256, 0, stream>>>(query, Kbuf, Vbuf, pe, Tk, Tv, Ts,
                                                         aw_buf, outpre);
  aw_avg_kernel<<<256, 256, 0, stream>>>(aw_buf, out + 4194304);
  gemm_nt_kernel<<<dim3(16, 32), 256, 0, stream>>>(outpre, Wo, bo, out, 4096, 1024, 1024);
}

// Round 2
// 379.583 us; speedup vs baseline: 2.0985x; 2.0985x over previous
//
#include <hip/hip_runtime.h>
#include <cstddef>

#define N_TOK 2048
#define BATCH 2
#define EMB   1024
#define NH    16
#define HD    64
#define NP    16
#define BHN   32
#define CHK   64
#define NCHK  32
#define SCALING 0.125f

typedef __attribute__((ext_vector_type(8))) short short8;
typedef __attribute__((ext_vector_type(4))) float f32x4;

__device__ __forceinline__ unsigned short f2bf(float f) {
  unsigned u = __float_as_uint(f);
  u += 0x7FFFu + ((u >> 16) & 1u);
  return (unsigned short)(u >> 16);
}
__device__ __forceinline__ float lo16(unsigned v) { return __uint_as_float(v << 16); }
__device__ __forceinline__ float hi16(unsigned v) { return __uint_as_float(v & 0xFFFF0000u); }

// ---------------- f32 -> bf16 convert ----------------
__global__ __launch_bounds__(256) void cvt_bf16_kernel(
    const float* __restrict__ src, unsigned short* __restrict__ dst, int n4)
{
  for (int i = blockIdx.x * 256 + threadIdx.x; i < n4; i += gridDim.x * 256) {
    const float4 v = *(const float4*)&src[(size_t)i * 4];
    ushort4 o;
    o.x = f2bf(v.x); o.y = f2bf(v.y); o.z = f2bf(v.z); o.w = f2bf(v.w);
    *(ushort4*)&dst[(size_t)i * 4] = o;
  }
}

// ---------------- bf16 MFMA NT GEMM: Y(MxN) = X(MxK) @ W(NxK)^T + bias ----------------
// 128x128 tile, 4 waves (2x2), each wave 64x64 via 4x4 fragments of 16x16x32.
template <bool BF16OUT>
__global__ __launch_bounds__(256) void mfma_gemm_nt(
    const unsigned short* __restrict__ Xb, const unsigned short* __restrict__ Wb,
    const float* __restrict__ bias, void* __restrict__ Yv, int M, int N, int K)
{
  __shared__ unsigned short As[128 * 40];   // row-major [128][32] padded to 40
  __shared__ unsigned short Bs[128 * 40];
  const int t = threadIdx.x;
  const int m0 = blockIdx.y * 128, n0 = blockIdx.x * 128;
  const int lane = t & 63, w = t >> 6, wr = w >> 1, wc = w & 1;
  const int srow = t >> 2, sk8 = (t & 3) << 3;
  const int rA = (wr * 64 + (lane & 15)) * 40 + ((lane >> 4) << 3);
  const int rB = (wc * 64 + (lane & 15)) * 40 + ((lane >> 4) << 3);
  f32x4 acc[4][4] = {};

  for (int k0 = 0; k0 < K; k0 += 32) {
    const uint4 a0 = *(const uint4*)&Xb[(size_t)(m0 + srow) * K + k0 + sk8];
    const uint4 a1 = *(const uint4*)&Xb[(size_t)(m0 + srow + 64) * K + k0 + sk8];
    const uint4 b0 = *(const uint4*)&Wb[(size_t)(n0 + srow) * K + k0 + sk8];
    const uint4 b1 = *(const uint4*)&Wb[(size_t)(n0 + srow + 64) * K + k0 + sk8];
    *(uint4*)&As[srow * 40 + sk8] = a0;
    *(uint4*)&As[(srow + 64) * 40 + sk8] = a1;
    *(uint4*)&Bs[srow * 40 + sk8] = b0;
    *(uint4*)&Bs[(srow + 64) * 40 + sk8] = b1;
    __syncthreads();
    short8 av[4], bv[4];
    #pragma unroll
    for (int m = 0; m < 4; ++m) av[m] = *(const short8*)&As[rA + m * 16 * 40];
    #pragma unroll
    for (int n = 0; n < 4; ++n) bv[n] = *(const short8*)&Bs[rB + n * 16 * 40];
    #pragma unroll
    for (int m = 0; m < 4; ++m)
      #pragma unroll
      for (int n = 0; n < 4; ++n)
        acc[m][n] = __builtin_amdgcn_mfma_f32_16x16x32_bf16(av[m], bv[n], acc[m][n], 0, 0, 0);
    __syncthreads();
  }

  // epilogue: C/D layout col=lane&15, row=(lane>>4)*4+reg
  float* Yf = (float*)Yv;
  unsigned short* Yb = (unsigned short*)Yv;
  #pragma unroll
  for (int n = 0; n < 4; ++n) {
    const int col = n0 + wc * 64 + n * 16 + (lane & 15);
    const float bcol = bias[col];
    #pragma unroll
    for (int m = 0; m < 4; ++m) {
      const int row0 = m0 + wr * 64 + m * 16 + ((lane >> 4) << 2);
      #pragma unroll
      for (int q = 0; q < 4; ++q) {
        const float val = acc[m][n][q] + bcol;
        if (BF16OUT) Yb[(size_t)(row0 + q) * N + col] = f2bf(val);
        else         Yf[(size_t)(row0 + q) * N + col] = val;
      }
    }
  }
}

// ---------------- pq projection ----------------
__global__ __launch_bounds__(256) void pq_proj_kernel(
    const float* __restrict__ pquery, const float* __restrict__ Wpq,
    const float* __restrict__ bpq, float* __restrict__ pq_s)
{
  const int r = blockIdx.x;          // r = p*BATCH + ib
  const int p = r >> 1, ib = r & 1;
  const int t = threadIdx.x;
  __shared__ float xs[EMB];
  for (int l = t; l < EMB; l += 256) xs[l] = pquery[(size_t)r * EMB + l];
  __syncthreads();
  for (int eo = 0; eo < 4; ++eo) {
    const int e = t + eo * 256;
    const float* wrow = &Wpq[(size_t)e * EMB];
    float acc = 0.f;
    for (int cc = 0; cc < EMB; cc += 4) {
      const float4 w4 = *(const float4*)&wrow[cc];
      acc += xs[cc] * w4.x + xs[cc + 1] * w4.y + xs[cc + 2] * w4.z + xs[cc + 3] * w4.w;
    }
    acc = (acc + bpq[e]) * SCALING;
    const int h = e >> 6, d = e & 63;
    pq_s[((size_t)(ib * NH + h) * NP + p) * HD + d] = acc;
  }
}

// ---------------- pattn logits ----------------
__global__ __launch_bounds__(256) void pattn_kernel(
    const float* __restrict__ query, const float* __restrict__ pq_s, float* __restrict__ pe)
{
  const int c = blockIdx.x, bh = blockIdx.y;
  const int ib = bh >> 4, h = bh & 15;
  const int t = threadIdx.x;
  const int i0 = c * CHK;
  __shared__ float qs[CHK][68];
  __shared__ float ps[NP][68];
  for (int l = t; l < CHK * 16; l += 256) {
    const int i = l >> 4, d4 = (l & 15) << 2;
    *(float4*)&qs[i][d4] =
        *(const float4*)&query[((size_t)(i0 + i) * BATCH + ib) * EMB + h * HD + d4];
  }
  {
    const int pp = t >> 4, d4 = (t & 15) << 2;
    *(float4*)&ps[pp][d4] = *(const float4*)&pq_s[((size_t)bh * NP + pp) * HD + d4];
  }
  __syncthreads();
  const int p = t & 15, ig = t >> 4;
  for (int rep = 0; rep < 4; ++rep) {
    const int i = rep * 16 + ig;
    float acc = 0.f;
    for (int d = 0; d < HD; ++d) acc += qs[i][d] * ps[p][d];
    pe[(size_t)bh * (N_TOK * NP) + (size_t)(i0 + i) * NP + p] = acc;
  }
}

// ---------------- column max + exp ----------------
__global__ __launch_bounds__(256) void colmax_exp_kernel(float* __restrict__ pe)
{
  const int bh = blockIdx.x;
  const int t = threadIdx.x;
  __shared__ float red[16][17];
  __shared__ float ms[16];
  const int p = t & 15, g = t >> 4;
  const size_t base = (size_t)bh * (N_TOK * NP);
  float mx = -3.0e38f;
  for (int i = g * 128; i < g * 128 + 128; ++i)
    mx = fmaxf(mx, pe[base + (size_t)i * NP + p]);
  red[g][p] = mx;
  __syncthreads();
  if (t < 16) {
    float m2 = red[0][t];
    for (int g2 = 1; g2 < 16; ++g2) m2 = fmaxf(m2, red[g2][t]);
    ms[t] = m2;
  }
  __syncthreads();
  for (int l = t; l < N_TOK * NP; l += 256)
    pe[base + l] = expf(pe[base + l] - ms[l & 15]);
}

// ---------------- per-chunk totals ----------------
__global__ __launch_bounds__(256) void chunk_totals_kernel(
    const float* __restrict__ pe, const unsigned short* __restrict__ Kbf,
    const unsigned short* __restrict__ Vbf, float* __restrict__ Tk,
    float* __restrict__ Tv, float* __restrict__ Ts)
{
  const int c = blockIdx.x, bh = blockIdx.y;
  const int ib = bh >> 4, h = bh & 15;
  const int t = threadIdx.x;
  const int i0 = c * CHK;
  __shared__ float Es[CHK][16];
  __shared__ float kv[CHK][68];
  for (int l = t; l < CHK * 16; l += 256)
    Es[l >> 4][l & 15] = pe[(size_t)bh * (N_TOK * NP) + (size_t)i0 * NP + l];
  for (int l = t; l < CHK * 8; l += 256) {
    const int i = l >> 3, d8 = (l & 7) << 3;
    const uint4 u = *(const uint4*)&Kbf[((size_t)(i0 + i) * BATCH + ib) * EMB + h * HD + d8];
    kv[i][d8 + 0] = lo16(u.x); kv[i][d8 + 1] = hi16(u.x);
    kv[i][d8 + 2] = lo16(u.y); kv[i][d8 + 3] = hi16(u.y);
    kv[i][d8 + 4] = lo16(u.z); kv[i][d8 + 5] = hi16(u.z);
    kv[i][d8 + 6] = lo16(u.w); kv[i][d8 + 7] = hi16(u.w);
  }
  __syncthreads();
  {
    const int p = t & 15, d0 = (t >> 4) * 4;
    float a0 = 0, a1 = 0, a2 = 0, a3 = 0;
    for (int j = 0; j < CHK; ++j) {
      const float e = Es[j][p];
      a0 += kv[j][d0] * e; a1 += kv[j][d0 + 1] * e;
      a2 += kv[j][d0 + 2] * e; a3 += kv[j][d0 + 3] * e;
    }
    const size_t tb = (size_t)(bh * NCHK + c) * 1024;
    Tk[tb + (d0 + 0) * 16 + p] = a0; Tk[tb + (d0 + 1) * 16 + p] = a1;
    Tk[tb + (d0 + 2) * 16 + p] = a2; Tk[tb + (d0 + 3) * 16 + p] = a3;
  }
  __syncthreads();
  for (int l = t; l < CHK * 8; l += 256) {
    const int i = l >> 3, d8 = (l & 7) << 3;
    const uint4 u = *(const uint4*)&Vbf[((size_t)(i0 + i) * BATCH + ib) * EMB + h * HD + d8];
    kv[i][d8 + 0] = lo16(u.x); kv[i][d8 + 1] = hi16(u.x);
    kv[i][d8 + 2] = lo16(u.y); kv[i][d8 + 3] = hi16(u.y);
    kv[i][d8 + 4] = lo16(u.z); kv[i][d8 + 5] = hi16(u.z);
    kv[i][d8 + 6] = lo16(u.w); kv[i][d8 + 7] = hi16(u.w);
  }
  __syncthreads();
  {
    const int p = t >> 4, d0 = (t & 15) * 4;
    float a0 = 0, a1 = 0, a2 = 0, a3 = 0;
    for (int j = 0; j < CHK; ++j) {
      const float e = Es[j][p];
      a0 += kv[j][d0] * e; a1 += kv[j][d0 + 1] * e;
      a2 += kv[j][d0 + 2] * e; a3 += kv[j][d0 + 3] * e;
    }
    const size_t tb = (size_t)(bh * NCHK + c) * 1024;
    float4 rr; rr.x = a0; rr.y = a1; rr.z = a2; rr.w = a3;
    *(float4*)&Tv[tb + p * 64 + d0] = rr;
  }
  if (t < 16) {
    float s = 0.f;
    for (int j = 0; j < CHK; ++j) s += Es[j][t];
    Ts[(size_t)(bh * NCHK + c) * 16 + t] = s;
  }
}

// ---------------- exclusive scan over chunks ----------------
__global__ __launch_bounds__(256) void chunk_scan_kernel(
    float* __restrict__ Tk, float* __restrict__ Tv, float* __restrict__ Ts)
{
  const int bh = blockIdx.x, t = threadIdx.x;
  for (int e = t; e < 1024; e += 256) {
    const size_t base = (size_t)bh * (NCHK * 1024) + e;
    float run = 0.f;
    for (int c = 0; c < NCHK; ++c) { const float v = Tk[base + c * 1024]; Tk[base + c * 1024] = run; run += v; }
    run = 0.f;
    for (int c = 0; c < NCHK; ++c) { const float v = Tv[base + c * 1024]; Tv[base + c * 1024] = run; run += v; }
  }
  if (t < 16) {
    const size_t base = (size_t)bh * (NCHK * 16) + t;
    float run = 0.f;
    for (int c = 0; c < NCHK; ++c) { const float v = Ts[base + c * 16]; Ts[base + c * 16] = run; run += v; }
  }
}

// ---------------- within-chunk causal attention ----------------
__global__ __launch_bounds__(256) void chunk_attn_kernel(
    const float* __restrict__ query, const unsigned short* __restrict__ Kbf,
    const unsigned short* __restrict__ Vbf, const float* __restrict__ pe,
    const float* __restrict__ Tk, const float* __restrict__ Tv,
    const float* __restrict__ Ts, float* __restrict__ aw_buf,
    unsigned short* __restrict__ outpre)
{
  const int c = blockIdx.x, bh = blockIdx.y;
  const int ib = bh >> 4, h = bh & 15;
  const int t = threadIdx.x;
  const int i0 = c * CHK;

  __shared__ float Qs[CHK][65];
  __shared__ float Ks[CHK][65];   // k, later reused for v
  __shared__ float Es[CHK][16];
  __shared__ float As[CHK][33];
  __shared__ float Nb[HD][16];
  __shared__ float Mb[16][68];
  __shared__ float Sb[16];
  __shared__ float gs[CHK][17];

  for (int l = t; l < CHK * 16; l += 256) {
    const int i = l >> 4, d4 = (l & 15) << 2;
    const float4 q4 = *(const float4*)&query[((size_t)(i0 + i) * BATCH + ib) * EMB + h * HD + d4];
    Qs[i][d4] = q4.x * SCALING; Qs[i][d4 + 1] = q4.y * SCALING;
    Qs[i][d4 + 2] = q4.z * SCALING; Qs[i][d4 + 3] = q4.w * SCALING;
  }
  for (int l = t; l < CHK * 8; l += 256) {
    const int i = l >> 3, d8 = (l & 7) << 3;
    const uint4 u = *(const uint4*)&Kbf[((size_t)(i0 + i) * BATCH + ib) * EMB + h * HD + d8];
    Ks[i][d8 + 0] = lo16(u.x); Ks[i][d8 + 1] = hi16(u.x);
    Ks[i][d8 + 2] = lo16(u.y); Ks[i][d8 + 3] = hi16(u.y);
    Ks[i][d8 + 4] = lo16(u.z); Ks[i][d8 + 5] = hi16(u.z);
    Ks[i][d8 + 6] = lo16(u.w); Ks[i][d8 + 7] = hi16(u.w);
  }
  for (int l = t; l < CHK * 16; l += 256)
    Es[l >> 4][l & 15] = pe[(size_t)bh * (N_TOK * NP) + (size_t)i0 * NP + l];
  for (int l = t; l < 1024; l += 256) Nb[l >> 4][l & 15] = Tk[(size_t)(bh * NCHK + c) * 1024 + l];
  for (int l = t; l < 1024; l += 256) Mb[l >> 6][l & 63] = Tv[(size_t)(bh * NCHK + c) * 1024 + l];
  if (t < 16) Sb[t] = Ts[(size_t)(bh * NCHK + c) * 16 + t];
  __syncthreads();

  const int p = t & 15, ig = t >> 4;     // stage owner (i = rep*16+ig, p)
  const int r = t & 31, cb = t >> 5;     // tile-compute owner

  // ---- stage 1
  float W1[4], Sc[4];
  #pragma unroll
  for (int rep = 0; rep < 4; ++rep) {
    const int i = rep * 16 + ig;
    float acc = 0.f;
    for (int d = 0; d < HD; ++d) acc += Qs[i][d] * Nb[d][p];
    W1[rep] = acc;
    Sc[rep] = Sb[p];
  }

  for (int jb = 0; jb < 2; ++jb) {
    {
      const int jr = jb * 32 + cb;
      float a00 = 0, a01 = 0, a02 = 0, a03 = 0, a10 = 0, a11 = 0, a12 = 0, a13 = 0;
      for (int d = 0; d < HD; ++d) {
        const float q0 = Qs[r][d], q1 = Qs[r + 32][d];
        const float k0 = Ks[jr][d], k1 = Ks[jr + 8][d], k2 = Ks[jr + 16][d], k3 = Ks[jr + 24][d];
        a00 += q0 * k0; a01 += q0 * k1; a02 += q0 * k2; a03 += q0 * k3;
        a10 += q1 * k0; a11 += q1 * k1; a12 += q1 * k2; a13 += q1 * k3;
      }
      As[r][cb] = a00; As[r][cb + 8] = a01; As[r][cb + 16] = a02; As[r][cb + 24] = a03;
      As[r + 32][cb] = a10; As[r + 32][cb + 8] = a11; As[r + 32][cb + 16] = a12; As[r + 32][cb + 24] = a13;
    }
    __syncthreads();
    const int j0 = jb * 32;
    for (int jj = 0; jj < 32; ++jj) {
      const int j = j0 + jj;
      const float e = Es[j][p];
      #pragma unroll
      for (int rep = 0; rep < 4; ++rep) {
        const int i = rep * 16 + ig;
        if (i > j) { W1[rep] += As[i][jj] * e; Sc[rep] += e; }
      }
    }
    __syncthreads();
  }

  // ---- finalize stage 1
  #pragma unroll
  for (int rep = 0; rep < 4; ++rep) {
    const int i = rep * 16 + ig;
    const float s = Sc[rep];
    const float ssafe = (s > 0.f) ? s : 1.f;
    const float wv = W1[rep] / ssafe;
    float m = wv;
    #pragma unroll
    for (int off = 1; off < 16; off <<= 1) m = fmaxf(m, __shfl_xor(m, off, 64));
    const float e = expf(wv - m);
    float ss = e;
    #pragma unroll
    for (int off = 1; off < 16; off <<= 1) ss += __shfl_xor(ss, off, 64);
    const float aw = e / ss;
    aw_buf[(size_t)bh * (N_TOK * NP) + (size_t)(i0 + i) * NP + p] = aw;
    gs[i][p] = aw / ssafe;
  }

  // ---- reload V into Ks
  __syncthreads();
  for (int l = t; l < CHK * 8; l += 256) {
    const int i = l >> 3, d8 = (l & 7) << 3;
    const uint4 u = *(const uint4*)&Vbf[((size_t)(i0 + i) * BATCH + ib) * EMB + h * HD + d8];
    Ks[i][d8 + 0] = lo16(u.x); Ks[i][d8 + 1] = hi16(u.x);
    Ks[i][d8 + 2] = lo16(u.y); Ks[i][d8 + 3] = hi16(u.y);
    Ks[i][d8 + 4] = lo16(u.z); Ks[i][d8 + 5] = hi16(u.z);
    Ks[i][d8 + 6] = lo16(u.w); Ks[i][d8 + 7] = hi16(u.w);
  }
  __syncthreads();

  // ---- stage 2
  const int db = (t & 15) << 2;
  float o[4][4] = {{0.f}};
  for (int jb = 0; jb < 2; ++jb) {
    {
      const int jr = jb * 32 + cb;
      float a00 = 0, a01 = 0, a02 = 0, a03 = 0, a10 = 0, a11 = 0, a12 = 0, a13 = 0;
      for (int pp = 0; pp < 16; ++pp) {
        const float g0 = gs[r][pp], g1 = gs[r + 32][pp];
        const float e0 = Es[jr][pp], e1 = Es[jr + 8][pp], e2 = Es[jr + 16][pp], e3 = Es[jr + 24][pp];
        a00 += g0 * e0; a01 += g0 * e1; a02 += g0 * e2; a03 += g0 * e3;
        a10 += g1 * e0; a11 += g1 * e1; a12 += g1 * e2; a13 += g1 * e3;
      }
      As[r][cb] = a00; As[r][cb + 8] = a01; As[r][cb + 16] = a02; As[r][cb + 24] = a03;
      As[r + 32][cb] = a10; As[r + 32][cb + 8] = a11; As[r + 32][cb + 16] = a12; As[r + 32][cb + 24] = a13;
    }
    __syncthreads();
    const int j0 = jb * 32;
    for (int jj = 0; jj < 32; ++jj) {
      const int j = j0 + jj;
      const float k0 = Ks[j][db], k1 = Ks[j][db + 1], k2 = Ks[j][db + 2], k3 = Ks[j][db + 3];
      #pragma unroll
      for (int rep = 0; rep < 4; ++rep) {
        const int i = rep * 16 + ig;
        if (i > j) {
          const float bb = As[i][jj];
          o[rep][0] += bb * k0; o[rep][1] += bb * k1;
          o[rep][2] += bb * k2; o[rep][3] += bb * k3;
        }
      }
    }
    __syncthreads();
  }

  // ---- Mb term + bf16 write
  #pragma unroll
  for (int rep = 0; rep < 4; ++rep) {
    const int i = rep * 16 + ig;
    float o0 = o[rep][0], o1 = o[rep][1], o2 = o[rep][2], o3 = o[rep][3];
    for (int pp = 0; pp < 16; ++pp) {
      const float gg = gs[i][pp];
      o0 += gg * Mb[pp][db]; o1 += gg * Mb[pp][db + 1];
      o2 += gg * Mb[pp][db + 2]; o3 += gg * Mb[pp][db + 3];
    }
    ushort4 ov;
    ov.x = f2bf(o0); ov.y = f2bf(o1); ov.z = f2bf(o2); ov.w = f2bf(o3);
    *(ushort4*)&outpre[((size_t)(i0 + i) * BATCH + ib) * EMB + h * HD + db] = ov;
  }
}

// ---------------- aw mean over heads ----------------
__global__ __launch_bounds__(256) void aw_avg_kernel(
    const float* __restrict__ aw_buf, float* __restrict__ out_aw)
{
  const int idx = blockIdx.x * 256 + threadIdx.x;
  const int p = idx & 15;
  const int i = (idx >> 4) & 2047;
  const int ib = idx >> 15;
  float s = 0.f;
  for (int hh = 0; hh < NH; ++hh)
    s += aw_buf[((size_t)(ib * NH + hh) * N_TOK + i) * NP + p];
  out_aw[idx] = s * (1.f / 16.f);
}

extern "C" void kernel_launch(void* const* d_in, const int* in_sizes, int n_in,
                              void* d_out, int out_size, void* d_ws, size_t ws_size,
                              hipStream_t stream) {
  const float* query  = (const float*)d_in[0];
  const float* pquery = (const float*)d_in[1];
  const float* Wpq    = (const float*)d_in[2];
  const float* bpq    = (const float*)d_in[3];
  const float* Wk     = (const float*)d_in[4];
  const float* bk     = (const float*)d_in[5];
  const float* Wv     = (const float*)d_in[6];
  const float* bv     = (const float*)d_in[7];
  const float* Wo     = (const float*)d_in[8];
  const float* bo     = (const float*)d_in[9];
  float* out = (float*)d_out;
  float* ws  = (float*)d_ws;

  float* pq_s   = ws;                       // 32768
  float* pe     = pq_s + 32768;             // 1048576
  float* aw_buf = pe + 1048576;             // 1048576
  float* Tk     = aw_buf + 1048576;         // 1048576
  float* Tv     = Tk + 1048576;             // 1048576
  float* Ts     = Tv + 1048576;             // 16384
  unsigned short* qbf    = (unsigned short*)(Ts + 16384);  // 4194304 bf16
  unsigned short* Kbf    = qbf + 4194304;
  unsigned short* Vbf    = Kbf + 4194304;
  unsigned short* wkbf   = Vbf + 4194304;   // 1048576 bf16
  unsigned short* wvbf   = wkbf + 1048576;
  unsigned short* wobf   = wvbf + 1048576;
  unsigned short* opbf   = wobf + 1048576;  // 4194304 bf16

  cvt_bf16_kernel<<<1024, 256, 0, stream>>>(query, qbf, 1048576);
  cvt_bf16_kernel<<<256, 256, 0, stream>>>(Wk, wkbf, 262144);
  cvt_bf16_kernel<<<256, 256, 0, stream>>>(Wv, wvbf, 262144);
  cvt_bf16_kernel<<<256, 256, 0, stream>>>(Wo, wobf, 262144);
  pq_proj_kernel<<<32, 256, 0, stream>>>(pquery, Wpq, bpq, pq_s);
  mfma_gemm_nt<true><<<dim3(8, 32), 256, 0, stream>>>(qbf, wkbf, bk, Kbf, 4096, 1024, 1024);
  mfma_gemm_nt<true><<<dim3(8, 32), 256, 0, stream>>>(qbf, wvbf, bv, Vbf, 4096, 1024, 1024);
  pattn_kernel<<<dim3(NCHK, BHN), 256, 0, stream>>>(query, pq_s, pe);
  colmax_exp_kernel<<<BHN, 256, 0, stream>>>(pe);
  chunk_totals_kernel<<<dim3(NCHK, BHN), 256, 0, stream>>>(pe, Kbf, Vbf, Tk, Tv, Ts);
  chunk_scan_kernel<<<BHN, 256, 0, stream>>>(Tk, Tv, Ts);
  chunk_attn_kernel<<<dim3(NCHK, BHN), 256, 0, stream>>>(query, Kbf, Vbf, pe, Tk, Tv, Ts,
                                                         aw_buf, opbf);
  aw_avg_kernel<<<256, 256, 0, stream>>>(aw_buf, out + 4194304);
  mfma_gemm_nt<false><<<dim3(8, 32), 256, 0, stream>>>(opbf, wobf, bo, out, 4096, 1024, 1024);
}

// Round 3
// 238.610 us; speedup vs baseline: 3.3383x; 1.5908x over previous
//
#include <hip/hip_runtime.h>
#include <cstddef>

#define N_TOK 2048
#define BATCH 2
#define EMB   1024
#define NH    16
#define HD    64
#define NP    16
#define BHN   32
#define CHK   64
#define NCHK  32
#define SCALING 0.125f

typedef __attribute__((ext_vector_type(8))) short short8;
typedef __attribute__((ext_vector_type(4))) float f32x4;

__device__ __forceinline__ unsigned short f2bf(float f) {
  unsigned u = __float_as_uint(f);
  u += 0x7FFFu + ((u >> 16) & 1u);
  return (unsigned short)(u >> 16);
}
__device__ __forceinline__ float lo16(unsigned v) { return __uint_as_float(v << 16); }
__device__ __forceinline__ float hi16(unsigned v) { return __uint_as_float(v & 0xFFFF0000u); }

// ---------------- f32 -> bf16 convert ----------------
__global__ __launch_bounds__(256) void cvt_bf16_kernel(
    const float* __restrict__ src, unsigned short* __restrict__ dst, int n4)
{
  for (int i = blockIdx.x * 256 + threadIdx.x; i < n4; i += gridDim.x * 256) {
    const float4 v = *(const float4*)&src[(size_t)i * 4];
    ushort4 o;
    o.x = f2bf(v.x); o.y = f2bf(v.y); o.z = f2bf(v.z); o.w = f2bf(v.w);
    *(ushort4*)&dst[(size_t)i * 4] = o;
  }
}

// ---------------- bf16 MFMA NT GEMM: Y(MxN) = X(MxK) @ W(NxK)^T + bias ----------------
template <bool BF16OUT>
__global__ __launch_bounds__(256) void mfma_gemm_nt(
    const unsigned short* __restrict__ Xb, const unsigned short* __restrict__ Wb,
    const float* __restrict__ bias, void* __restrict__ Yv, int M, int N, int K)
{
  __shared__ unsigned short As[128 * 40];
  __shared__ unsigned short Bs[128 * 40];
  const int t = threadIdx.x;
  const int m0 = blockIdx.y * 128, n0 = blockIdx.x * 128;
  const int lane = t & 63, w = t >> 6, wr = w >> 1, wc = w & 1;
  const int srow = t >> 2, sk8 = (t & 3) << 3;
  const int rA = (wr * 64 + (lane & 15)) * 40 + ((lane >> 4) << 3);
  const int rB = (wc * 64 + (lane & 15)) * 40 + ((lane >> 4) << 3);
  f32x4 acc[4][4] = {};

  for (int k0 = 0; k0 < K; k0 += 32) {
    const uint4 a0 = *(const uint4*)&Xb[(size_t)(m0 + srow) * K + k0 + sk8];
    const uint4 a1 = *(const uint4*)&Xb[(size_t)(m0 + srow + 64) * K + k0 + sk8];
    const uint4 b0 = *(const uint4*)&Wb[(size_t)(n0 + srow) * K + k0 + sk8];
    const uint4 b1 = *(const uint4*)&Wb[(size_t)(n0 + srow + 64) * K + k0 + sk8];
    *(uint4*)&As[srow * 40 + sk8] = a0;
    *(uint4*)&As[(srow + 64) * 40 + sk8] = a1;
    *(uint4*)&Bs[srow * 40 + sk8] = b0;
    *(uint4*)&Bs[(srow + 64) * 40 + sk8] = b1;
    __syncthreads();
    short8 av[4], bv[4];
    #pragma unroll
    for (int m = 0; m < 4; ++m) av[m] = *(const short8*)&As[rA + m * 16 * 40];
    #pragma unroll
    for (int n = 0; n < 4; ++n) bv[n] = *(const short8*)&Bs[rB + n * 16 * 40];
    #pragma unroll
    for (int m = 0; m < 4; ++m)
      #pragma unroll
      for (int n = 0; n < 4; ++n)
        acc[m][n] = __builtin_amdgcn_mfma_f32_16x16x32_bf16(av[m], bv[n], acc[m][n], 0, 0, 0);
    __syncthreads();
  }

  float* Yf = (float*)Yv;
  unsigned short* Yb = (unsigned short*)Yv;
  #pragma unroll
  for (int n = 0; n < 4; ++n) {
    const int col = n0 + wc * 64 + n * 16 + (lane & 15);
    const float bcol = bias[col];
    #pragma unroll
    for (int m = 0; m < 4; ++m) {
      const int row0 = m0 + wr * 64 + m * 16 + ((lane >> 4) << 2);
      #pragma unroll
      for (int q = 0; q < 4; ++q) {
        const float val = acc[m][n][q] + bcol;
        if (BF16OUT) Yb[(size_t)(row0 + q) * N + col] = f2bf(val);
        else         Yf[(size_t)(row0 + q) * N + col] = val;
      }
    }
  }
}

// ---------------- pq projection (split-K, 512 blocks) ----------------
__global__ __launch_bounds__(256) void pq_proj_kernel(
    const float* __restrict__ pquery, const float* __restrict__ Wpq,
    const float* __restrict__ bpq, float* __restrict__ pq_s)
{
  const int r = blockIdx.x;          // r = p*BATCH + ib
  const int p = r >> 1, ib = r & 1;
  const int seg = blockIdx.y;        // e chunk of 64
  const int t = threadIdx.x;
  const int el = t & 63, ks = t >> 6;
  const int e = seg * 64 + el;
  __shared__ float xs[EMB];
  __shared__ float part[4][64];
  for (int l = t; l < EMB; l += 256) xs[l] = pquery[(size_t)r * EMB + l];
  __syncthreads();
  const float* wrow = &Wpq[(size_t)e * EMB + ks * 256];
  const float* xp = &xs[ks * 256];
  float acc = 0.f;
  #pragma unroll 8
  for (int cc = 0; cc < 256; cc += 4) {
    const float4 w4 = *(const float4*)&wrow[cc];
    acc += xp[cc] * w4.x + xp[cc + 1] * w4.y + xp[cc + 2] * w4.z + xp[cc + 3] * w4.w;
  }
  part[ks][el] = acc;
  __syncthreads();
  if (ks == 0) {
    float s = part[0][el] + part[1][el] + part[2][el] + part[3][el];
    s = (s + bpq[e]) * SCALING;
    const int h = e >> 6, d = e & 63;
    pq_s[((size_t)(ib * NH + h) * NP + p) * HD + d] = s;
  }
}

// ---------------- pattn logits ----------------
__global__ __launch_bounds__(256) void pattn_kernel(
    const float* __restrict__ query, const float* __restrict__ pq_s, float* __restrict__ pe)
{
  const int c = blockIdx.x, bh = blockIdx.y;
  const int ib = bh >> 4, h = bh & 15;
  const int t = threadIdx.x;
  const int i0 = c * CHK;
  __shared__ float qs[CHK][68];
  __shared__ float ps[NP][68];
  for (int l = t; l < CHK * 16; l += 256) {
    const int i = l >> 4, d4 = (l & 15) << 2;
    *(float4*)&qs[i][d4] =
        *(const float4*)&query[((size_t)(i0 + i) * BATCH + ib) * EMB + h * HD + d4];
  }
  {
    const int pp = t >> 4, d4 = (t & 15) << 2;
    *(float4*)&ps[pp][d4] = *(const float4*)&pq_s[((size_t)bh * NP + pp) * HD + d4];
  }
  __syncthreads();
  const int p = t & 15, ig = t >> 4;
  for (int rep = 0; rep < 4; ++rep) {
    const int i = rep * 16 + ig;
    float acc = 0.f;
    for (int d = 0; d < HD; ++d) acc += qs[i][d] * ps[p][d];
    pe[(size_t)bh * (N_TOK * NP) + (size_t)(i0 + i) * NP + p] = acc;
  }
}

// ---------------- partial column max (512 blocks) ----------------
__global__ __launch_bounds__(256) void colmax_part_kernel(
    const float* __restrict__ pe, float* __restrict__ red)
{
  const int seg = blockIdx.x, bh = blockIdx.y;   // seg: 128 rows
  const int t = threadIdx.x;
  const int p = t & 15, g = t >> 4;
  __shared__ float rs[16][17];
  const size_t base = (size_t)bh * (N_TOK * NP) + (size_t)seg * 128 * NP;
  float mx = -3.0e38f;
  for (int i = g * 8; i < g * 8 + 8; ++i)
    mx = fmaxf(mx, pe[base + (size_t)i * NP + p]);
  rs[g][p] = mx;
  __syncthreads();
  if (t < 16) {
    float m2 = rs[0][t];
    #pragma unroll
    for (int g2 = 1; g2 < 16; ++g2) m2 = fmaxf(m2, rs[g2][t]);
    red[((size_t)bh * 16 + seg) * 16 + t] = m2;
  }
}

// ---------------- final max reduce + exp apply (512 blocks) ----------------
__global__ __launch_bounds__(256) void colmax_apply_kernel(
    float* __restrict__ pe, const float* __restrict__ red)
{
  const int seg = blockIdx.x, bh = blockIdx.y;
  const int t = threadIdx.x;
  __shared__ float ms[16];
  if (t < 16) {
    float m2 = -3.0e38f;
    #pragma unroll
    for (int s = 0; s < 16; ++s) m2 = fmaxf(m2, red[((size_t)bh * 16 + s) * 16 + t]);
    ms[t] = m2;
  }
  __syncthreads();
  const size_t base = (size_t)bh * (N_TOK * NP) + (size_t)seg * 128 * NP;
  for (int l = t; l < 128 * NP; l += 256)
    pe[base + l] = expf(pe[base + l] - ms[l & 15]);
}

// ---------------- per-chunk totals ----------------
__global__ __launch_bounds__(256) void chunk_totals_kernel(
    const float* __restrict__ pe, const unsigned short* __restrict__ Kbf,
    const unsigned short* __restrict__ Vbf, float* __restrict__ Tk,
    float* __restrict__ Tv, float* __restrict__ Ts)
{
  const int c = blockIdx.x, bh = blockIdx.y;
  const int ib = bh >> 4, h = bh & 15;
  const int t = threadIdx.x;
  const int i0 = c * CHK;
  __shared__ float Es[CHK][16];
  __shared__ float kv[CHK][68];
  for (int l = t; l < CHK * 16; l += 256)
    Es[l >> 4][l & 15] = pe[(size_t)bh * (N_TOK * NP) + (size_t)i0 * NP + l];
  for (int l = t; l < CHK * 8; l += 256) {
    const int i = l >> 3, d8 = (l & 7) << 3;
    const uint4 u = *(const uint4*)&Kbf[((size_t)(i0 + i) * BATCH + ib) * EMB + h * HD + d8];
    kv[i][d8 + 0] = lo16(u.x); kv[i][d8 + 1] = hi16(u.x);
    kv[i][d8 + 2] = lo16(u.y); kv[i][d8 + 3] = hi16(u.y);
    kv[i][d8 + 4] = lo16(u.z); kv[i][d8 + 5] = hi16(u.z);
    kv[i][d8 + 6] = lo16(u.w); kv[i][d8 + 7] = hi16(u.w);
  }
  __syncthreads();
  {
    const int p = t & 15, d0 = (t >> 4) * 4;
    float a0 = 0, a1 = 0, a2 = 0, a3 = 0;
    for (int j = 0; j < CHK; ++j) {
      const float e = Es[j][p];
      a0 += kv[j][d0] * e; a1 += kv[j][d0 + 1] * e;
      a2 += kv[j][d0 + 2] * e; a3 += kv[j][d0 + 3] * e;
    }
    const size_t tb = (size_t)(bh * NCHK + c) * 1024;
    Tk[tb + (d0 + 0) * 16 + p] = a0; Tk[tb + (d0 + 1) * 16 + p] = a1;
    Tk[tb + (d0 + 2) * 16 + p] = a2; Tk[tb + (d0 + 3) * 16 + p] = a3;
  }
  __syncthreads();
  for (int l = t; l < CHK * 8; l += 256) {
    const int i = l >> 3, d8 = (l & 7) << 3;
    const uint4 u = *(const uint4*)&Vbf[((size_t)(i0 + i) * BATCH + ib) * EMB + h * HD + d8];
    kv[i][d8 + 0] = lo16(u.x); kv[i][d8 + 1] = hi16(u.x);
    kv[i][d8 + 2] = lo16(u.y); kv[i][d8 + 3] = hi16(u.y);
    kv[i][d8 + 4] = lo16(u.z); kv[i][d8 + 5] = hi16(u.z);
    kv[i][d8 + 6] = lo16(u.w); kv[i][d8 + 7] = hi16(u.w);
  }
  __syncthreads();
  {
    const int p = t >> 4, d0 = (t & 15) * 4;
    float a0 = 0, a1 = 0, a2 = 0, a3 = 0;
    for (int j = 0; j < CHK; ++j) {
      const float e = Es[j][p];
      a0 += kv[j][d0] * e; a1 += kv[j][d0 + 1] * e;
      a2 += kv[j][d0 + 2] * e; a3 += kv[j][d0 + 3] * e;
    }
    const size_t tb = (size_t)(bh * NCHK + c) * 1024;
    float4 rr; rr.x = a0; rr.y = a1; rr.z = a2; rr.w = a3;
    *(float4*)&Tv[tb + p * 64 + d0] = rr;
  }
  if (t < 16) {
    float s = 0.f;
    for (int j = 0; j < CHK; ++j) s += Es[j][t];
    Ts[(size_t)(bh * NCHK + c) * 16 + t] = s;
  }
}

// ---------------- exclusive scan over chunks (256 blocks) ----------------
__global__ __launch_bounds__(256) void chunk_scan_kernel(
    float* __restrict__ Tk, float* __restrict__ Tv, float* __restrict__ Ts)
{
  const int bh = blockIdx.x, y = blockIdx.y, t = threadIdx.x;
  const int slot = y * 256 + t;            // 0..2047
  float* arr = (slot < 1024) ? Tk : Tv;
  const int e = slot & 1023;
  const size_t base = (size_t)bh * (NCHK * 1024) + e;
  float v[NCHK];
  #pragma unroll
  for (int c = 0; c < NCHK; ++c) v[c] = arr[base + (size_t)c * 1024];
  float run = 0.f;
  #pragma unroll
  for (int c = 0; c < NCHK; ++c) { arr[base + (size_t)c * 1024] = run; run += v[c]; }
  if (y == 7 && t < 16) {
    const size_t sb = (size_t)bh * (NCHK * 16) + t;
    float s[NCHK];
    #pragma unroll
    for (int c = 0; c < NCHK; ++c) s[c] = Ts[sb + c * 16];
    float rs = 0.f;
    #pragma unroll
    for (int c = 0; c < NCHK; ++c) { Ts[sb + c * 16] = rs; rs += s[c]; }
  }
}

// ---------------- within-chunk causal attention ----------------
__global__ __launch_bounds__(256) void chunk_attn_kernel(
    const float* __restrict__ query, const unsigned short* __restrict__ Kbf,
    const unsigned short* __restrict__ Vbf, const float* __restrict__ pe,
    const float* __restrict__ Tk, const float* __restrict__ Tv,
    const float* __restrict__ Ts, float* __restrict__ aw_buf,
    unsigned short* __restrict__ outpre)
{
  const int c = blockIdx.x, bh = blockIdx.y;
  const int ib = bh >> 4, h = bh & 15;
  const int t = threadIdx.x;
  const int i0 = c * CHK;

  __shared__ float Qs[CHK][65];
  __shared__ float Ks[CHK][65];
  __shared__ float Es[CHK][16];
  __shared__ float As[CHK][33];
  __shared__ float Nb[HD][16];
  __shared__ float Mb[16][68];
  __shared__ float Sb[16];
  __shared__ float gs[CHK][17];

  for (int l = t; l < CHK * 16; l += 256) {
    const int i = l >> 4, d4 = (l & 15) << 2;
    const float4 q4 = *(const float4*)&query[((size_t)(i0 + i) * BATCH + ib) * EMB + h * HD + d4];
    Qs[i][d4] = q4.x * SCALING; Qs[i][d4 + 1] = q4.y * SCALING;
    Qs[i][d4 + 2] = q4.z * SCALING; Qs[i][d4 + 3] = q4.w * SCALING;
  }
  for (int l = t; l < CHK * 8; l += 256) {
    const int i = l >> 3, d8 = (l & 7) << 3;
    const uint4 u = *(const uint4*)&Kbf[((size_t)(i0 + i) * BATCH + ib) * EMB + h * HD + d8];
    Ks[i][d8 + 0] = lo16(u.x); Ks[i][d8 + 1] = hi16(u.x);
    Ks[i][d8 + 2] = lo16(u.y); Ks[i][d8 + 3] = hi16(u.y);
    Ks[i][d8 + 4] = lo16(u.z); Ks[i][d8 + 5] = hi16(u.z);
    Ks[i][d8 + 6] = lo16(u.w); Ks[i][d8 + 7] = hi16(u.w);
  }
  for (int l = t; l < CHK * 16; l += 256)
    Es[l >> 4][l & 15] = pe[(size_t)bh * (N_TOK * NP) + (size_t)i0 * NP + l];
  for (int l = t; l < 1024; l += 256) Nb[l >> 4][l & 15] = Tk[(size_t)(bh * NCHK + c) * 1024 + l];
  for (int l = t; l < 1024; l += 256) Mb[l >> 6][l & 63] = Tv[(size_t)(bh * NCHK + c) * 1024 + l];
  if (t < 16) Sb[t] = Ts[(size_t)(bh * NCHK + c) * 16 + t];
  __syncthreads();

  const int p = t & 15, ig = t >> 4;
  const int r = t & 31, cb = t >> 5;

  float W1[4], Sc[4];
  #pragma unroll
  for (int rep = 0; rep < 4; ++rep) {
    const int i = rep * 16 + ig;
    float acc = 0.f;
    for (int d = 0; d < HD; ++d) acc += Qs[i][d] * Nb[d][p];
    W1[rep] = acc;
    Sc[rep] = Sb[p];
  }

  for (int jb = 0; jb < 2; ++jb) {
    {
      const int jr = jb * 32 + cb;
      float a00 = 0, a01 = 0, a02 = 0, a03 = 0, a10 = 0, a11 = 0, a12 = 0, a13 = 0;
      for (int d = 0; d < HD; ++d) {
        const float q0 = Qs[r][d], q1 = Qs[r + 32][d];
        const float k0 = Ks[jr][d], k1 = Ks[jr + 8][d], k2 = Ks[jr + 16][d], k3 = Ks[jr + 24][d];
        a00 += q0 * k0; a01 += q0 * k1; a02 += q0 * k2; a03 += q0 * k3;
        a10 += q1 * k0; a11 += q1 * k1; a12 += q1 * k2; a13 += q1 * k3;
      }
      As[r][cb] = a00; As[r][cb + 8] = a01; As[r][cb + 16] = a02; As[r][cb + 24] = a03;
      As[r + 32][cb] = a10; As[r + 32][cb + 8] = a11; As[r + 32][cb + 16] = a12; As[r + 32][cb + 24] = a13;
    }
    __syncthreads();
    const int j0 = jb * 32;
    for (int jj = 0; jj < 32; ++jj) {
      const int j = j0 + jj;
      const float e = Es[j][p];
      #pragma unroll
      for (int rep = 0; rep < 4; ++rep) {
        const int i = rep * 16 + ig;
        if (i > j) { W1[rep] += As[i][jj] * e; Sc[rep] += e; }
      }
    }
    __syncthreads();
  }

  #pragma unroll
  for (int rep = 0; rep < 4; ++rep) {
    const int i = rep * 16 + ig;
    const float s = Sc[rep];
    const float ssafe = (s > 0.f) ? s : 1.f;
    const float wv = W1[rep] / ssafe;
    float m = wv;
    #pragma unroll
    for (int off = 1; off < 16; off <<= 1) m = fmaxf(m, __shfl_xor(m, off, 64));
    const float e = expf(wv - m);
    float ss = e;
    #pragma unroll
    for (int off = 1; off < 16; off <<= 1) ss += __shfl_xor(ss, off, 64);
    const float aw = e / ss;
    aw_buf[(size_t)bh * (N_TOK * NP) + (size_t)(i0 + i) * NP + p] = aw;
    gs[i][p] = aw / ssafe;
  }

  __syncthreads();
  for (int l = t; l < CHK * 8; l += 256) {
    const int i = l >> 3, d8 = (l & 7) << 3;
    const uint4 u = *(const uint4*)&Vbf[((size_t)(i0 + i) * BATCH + ib) * EMB + h * HD + d8];
    Ks[i][d8 + 0] = lo16(u.x); Ks[i][d8 + 1] = hi16(u.x);
    Ks[i][d8 + 2] = lo16(u.y); Ks[i][d8 + 3] = hi16(u.y);
    Ks[i][d8 + 4] = lo16(u.z); Ks[i][d8 + 5] = hi16(u.z);
    Ks[i][d8 + 6] = lo16(u.w); Ks[i][d8 + 7] = hi16(u.w);
  }
  __syncthreads();

  const int db = (t & 15) << 2;
  float o[4][4] = {{0.f}};
  for (int jb = 0; jb < 2; ++jb) {
    {
      const int jr = jb * 32 + cb;
      float a00 = 0, a01 = 0, a02 = 0, a03 = 0, a10 = 0, a11 = 0, a12 = 0, a13 = 0;
      for (int pp = 0; pp < 16; ++pp) {
        const float g0 = gs[r][pp], g1 = gs[r + 32][pp];
        const float e0 = Es[jr][pp], e1 = Es[jr + 8][pp], e2 = Es[jr + 16][pp], e3 = Es[jr + 24][pp];
        a00 += g0 * e0; a01 += g0 * e1; a02 += g0 * e2; a03 += g0 * e3;
        a10 += g1 * e0; a11 += g1 * e1; a12 += g1 * e2; a13 += g1 * e3;
      }
      As[r][cb] = a00; As[r][cb + 8] = a01; As[r][cb + 16] = a02; As[r][cb + 24] = a03;
      As[r + 32][cb] = a10; As[r + 32][cb + 8] = a11; As[r + 32][cb + 16] = a12; As[r + 32][cb + 24] = a13;
    }
    __syncthreads();
    const int j0 = jb * 32;
    for (int jj = 0; jj < 32; ++jj) {
      const int j = j0 + jj;
      const float k0 = Ks[j][db], k1 = Ks[j][db + 1], k2 = Ks[j][db + 2], k3 = Ks[j][db + 3];
      #pragma unroll
      for (int rep = 0; rep < 4; ++rep) {
        const int i = rep * 16 + ig;
        if (i > j) {
          const float bb = As[i][jj];
          o[rep][0] += bb * k0; o[rep][1] += bb * k1;
          o[rep][2] += bb * k2; o[rep][3] += bb * k3;
        }
      }
    }
    __syncthreads();
  }

  #pragma unroll
  for (int rep = 0; rep < 4; ++rep) {
    const int i = rep * 16 + ig;
    float o0 = o[rep][0], o1 = o[rep][1], o2 = o[rep][2], o3 = o[rep][3];
    for (int pp = 0; pp < 16; ++pp) {
      const float gg = gs[i][pp];
      o0 += gg * Mb[pp][db]; o1 += gg * Mb[pp][db + 1];
      o2 += gg * Mb[pp][db + 2]; o3 += gg * Mb[pp][db + 3];
    }
    ushort4 ov;
    ov.x = f2bf(o0); ov.y = f2bf(o1); ov.z = f2bf(o2); ov.w = f2bf(o3);
    *(ushort4*)&outpre[((size_t)(i0 + i) * BATCH + ib) * EMB + h * HD + db] = ov;
  }
}

// ---------------- aw mean over heads ----------------
__global__ __launch_bounds__(256) void aw_avg_kernel(
    const float* __restrict__ aw_buf, float* __restrict__ out_aw)
{
  const int idx = blockIdx.x * 256 + threadIdx.x;
  const int p = idx & 15;
  const int i = (idx >> 4) & 2047;
  const int ib = idx >> 15;
  float s = 0.f;
  for (int hh = 0; hh < NH; ++hh)
    s += aw_buf[((size_t)(ib * NH + hh) * N_TOK + i) * NP + p];
  out_aw[idx] = s * (1.f / 16.f);
}

extern "C" void kernel_launch(void* const* d_in, const int* in_sizes, int n_in,
                              void* d_out, int out_size, void* d_ws, size_t ws_size,
                              hipStream_t stream) {
  const float* query  = (const float*)d_in[0];
  const float* pquery = (const float*)d_in[1];
  const float* Wpq    = (const float*)d_in[2];
  const float* bpq    = (const float*)d_in[3];
  const float* Wk     = (const float*)d_in[4];
  const float* bk     = (const float*)d_in[5];
  const float* Wv     = (const float*)d_in[6];
  const float* bv     = (const float*)d_in[7];
  const float* Wo     = (const float*)d_in[8];
  const float* bo     = (const float*)d_in[9];
  float* out = (float*)d_out;
  float* ws  = (float*)d_ws;

  float* pq_s   = ws;                       // 32768
  float* pe     = pq_s + 32768;             // 1048576
  float* aw_buf = pe + 1048576;             // 1048576
  float* Tk     = aw_buf + 1048576;         // 1048576
  float* Tv     = Tk + 1048576;             // 1048576
  float* Ts     = Tv + 1048576;             // 16384
  float* redm   = Ts + 16384;               // 32*16*16 = 8192
  unsigned short* qbf  = (unsigned short*)(redm + 8192);
  unsigned short* Kbf  = qbf + 4194304;
  unsigned short* Vbf  = Kbf + 4194304;
  unsigned short* wkbf = Vbf + 4194304;
  unsigned short* wvbf = wkbf + 1048576;
  unsigned short* wobf = wvbf + 1048576;
  unsigned short* opbf = wobf + 1048576;

  cvt_bf16_kernel<<<1024, 256, 0, stream>>>(query, qbf, 1048576);
  cvt_bf16_kernel<<<256, 256, 0, stream>>>(Wk, wkbf, 262144);
  cvt_bf16_kernel<<<256, 256, 0, stream>>>(Wv, wvbf, 262144);
  cvt_bf16_kernel<<<256, 256, 0, stream>>>(Wo, wobf, 262144);
  pq_proj_kernel<<<dim3(32, 16), 256, 0, stream>>>(pquery, Wpq, bpq, pq_s);
  mfma_gemm_nt<true><<<dim3(8, 32), 256, 0, stream>>>(qbf, wkbf, bk, Kbf, 4096, 1024, 1024);
  mfma_gemm_nt<true><<<dim3(8, 32), 256, 0, stream>>>(qbf, wvbf, bv, Vbf, 4096, 1024, 1024);
  pattn_kernel<<<dim3(NCHK, BHN), 256, 0, stream>>>(query, pq_s, pe);
  colmax_part_kernel<<<dim3(16, BHN), 256, 0, stream>>>(pe, redm);
  colmax_apply_kernel<<<dim3(16, BHN), 256, 0, stream>>>(pe, redm);
  chunk_totals_kernel<<<dim3(NCHK, BHN), 256, 0, stream>>>(pe, Kbf, Vbf, Tk, Tv, Ts);
  chunk_scan_kernel<<<dim3(BHN, 8), 256, 0, stream>>>(Tk, Tv, Ts);
  chunk_attn_kernel<<<dim3(NCHK, BHN), 256, 0, stream>>>(query, Kbf, Vbf, pe, Tk, Tv, Ts,
                                                         aw_buf, opbf);
  aw_avg_kernel<<<256, 256, 0, stream>>>(aw_buf, out + 4194304);
  mfma_gemm_nt<false><<<dim3(8, 32), 256, 0, stream>>>(opbf, wobf, bo, out, 4096, 1024, 1024);
}

// Round 4
// 171.333 us; speedup vs baseline: 4.6492x; 1.3927x over previous
//
#include <hip/hip_runtime.h>
#include <cstddef>

#define N_TOK 2048
#define BATCH 2
#define EMB   1024
#define NH    16
#define HD    64
#define NP    16
#define BHN   32
#define CHK   64
#define NCHK  32
#define SCALING 0.125f

typedef __attribute__((ext_vector_type(8))) short short8;
typedef __attribute__((ext_vector_type(4))) float f32x4;

__device__ __forceinline__ unsigned short f2bf(float f) {
  unsigned u = __float_as_uint(f);
  u += 0x7FFFu + ((u >> 16) & 1u);
  return (unsigned short)(u >> 16);
}

// ---------------- f32 -> bf16 convert ----------------
__global__ __launch_bounds__(256) void cvt_bf16_kernel(
    const float* __restrict__ src, unsigned short* __restrict__ dst, int n4)
{
  for (int i = blockIdx.x * 256 + threadIdx.x; i < n4; i += gridDim.x * 256) {
    const float4 v = *(const float4*)&src[(size_t)i * 4];
    ushort4 o;
    o.x = f2bf(v.x); o.y = f2bf(v.y); o.z = f2bf(v.z); o.w = f2bf(v.w);
    *(ushort4*)&dst[(size_t)i * 4] = o;
  }
}

// ---------------- bf16 MFMA NT GEMM ----------------
template <bool BF16OUT>
__global__ __launch_bounds__(256) void mfma_gemm_nt(
    const unsigned short* __restrict__ Xb, const unsigned short* __restrict__ Wb,
    const float* __restrict__ bias, void* __restrict__ Yv, int M, int N, int K)
{
  __shared__ unsigned short As[128 * 40];
  __shared__ unsigned short Bs[128 * 40];
  const int t = threadIdx.x;
  const int m0 = blockIdx.y * 128, n0 = blockIdx.x * 128;
  const int lane = t & 63, w = t >> 6, wr = w >> 1, wc = w & 1;
  const int srow = t >> 2, sk8 = (t & 3) << 3;
  const int rA = (wr * 64 + (lane & 15)) * 40 + ((lane >> 4) << 3);
  const int rB = (wc * 64 + (lane & 15)) * 40 + ((lane >> 4) << 3);
  f32x4 acc[4][4] = {};

  for (int k0 = 0; k0 < K; k0 += 32) {
    const uint4 a0 = *(const uint4*)&Xb[(size_t)(m0 + srow) * K + k0 + sk8];
    const uint4 a1 = *(const uint4*)&Xb[(size_t)(m0 + srow + 64) * K + k0 + sk8];
    const uint4 b0 = *(const uint4*)&Wb[(size_t)(n0 + srow) * K + k0 + sk8];
    const uint4 b1 = *(const uint4*)&Wb[(size_t)(n0 + srow + 64) * K + k0 + sk8];
    *(uint4*)&As[srow * 40 + sk8] = a0;
    *(uint4*)&As[(srow + 64) * 40 + sk8] = a1;
    *(uint4*)&Bs[srow * 40 + sk8] = b0;
    *(uint4*)&Bs[(srow + 64) * 40 + sk8] = b1;
    __syncthreads();
    short8 av[4], bv[4];
    #pragma unroll
    for (int m = 0; m < 4; ++m) av[m] = *(const short8*)&As[rA + m * 16 * 40];
    #pragma unroll
    for (int n = 0; n < 4; ++n) bv[n] = *(const short8*)&Bs[rB + n * 16 * 40];
    #pragma unroll
    for (int m = 0; m < 4; ++m)
      #pragma unroll
      for (int n = 0; n < 4; ++n)
        acc[m][n] = __builtin_amdgcn_mfma_f32_16x16x32_bf16(av[m], bv[n], acc[m][n], 0, 0, 0);
    __syncthreads();
  }

  float* Yf = (float*)Yv;
  unsigned short* Yb = (unsigned short*)Yv;
  #pragma unroll
  for (int n = 0; n < 4; ++n) {
    const int col = n0 + wc * 64 + n * 16 + (lane & 15);
    const float bcol = bias[col];
    #pragma unroll
    for (int m = 0; m < 4; ++m) {
      const int row0 = m0 + wr * 64 + m * 16 + ((lane >> 4) << 2);
      #pragma unroll
      for (int q = 0; q < 4; ++q) {
        const float val = acc[m][n][q] + bcol;
        if (BF16OUT) Yb[(size_t)(row0 + q) * N + col] = f2bf(val);
        else         Yf[(size_t)(row0 + q) * N + col] = val;
      }
    }
  }
}

// ---------------- pq projection (split-K, 512 blocks) ----------------
__global__ __launch_bounds__(256) void pq_proj_kernel(
    const float* __restrict__ pquery, const float* __restrict__ Wpq,
    const float* __restrict__ bpq, float* __restrict__ pq_s)
{
  const int r = blockIdx.x;
  const int p = r >> 1, ib = r & 1;
  const int seg = blockIdx.y;
  const int t = threadIdx.x;
  const int el = t & 63, ks = t >> 6;
  const int e = seg * 64 + el;
  __shared__ float xs[EMB];
  __shared__ float part[4][64];
  for (int l = t; l < EMB; l += 256) xs[l] = pquery[(size_t)r * EMB + l];
  __syncthreads();
  const float* wrow = &Wpq[(size_t)e * EMB + ks * 256];
  const float* xp = &xs[ks * 256];
  float acc = 0.f;
  #pragma unroll 8
  for (int cc = 0; cc < 256; cc += 4) {
    const float4 w4 = *(const float4*)&wrow[cc];
    acc += xp[cc] * w4.x + xp[cc + 1] * w4.y + xp[cc + 2] * w4.z + xp[cc + 3] * w4.w;
  }
  part[ks][el] = acc;
  __syncthreads();
  if (ks == 0) {
    float s = part[0][el] + part[1][el] + part[2][el] + part[3][el];
    s = (s + bpq[e]) * SCALING;
    const int h = e >> 6, d = e & 63;
    pq_s[((size_t)(ib * NH + h) * NP + p) * HD + d] = s;
  }
}

// ---------------- pattn logits ----------------
__global__ __launch_bounds__(256) void pattn_kernel(
    const float* __restrict__ query, const float* __restrict__ pq_s, float* __restrict__ pe)
{
  const int c = blockIdx.x, bh = blockIdx.y;
  const int ib = bh >> 4, h = bh & 15;
  const int t = threadIdx.x;
  const int i0 = c * CHK;
  __shared__ float qs[CHK][68];
  __shared__ float ps[NP][68];
  for (int l = t; l < CHK * 16; l += 256) {
    const int i = l >> 4, d4 = (l & 15) << 2;
    *(float4*)&qs[i][d4] =
        *(const float4*)&query[((size_t)(i0 + i) * BATCH + ib) * EMB + h * HD + d4];
  }
  {
    const int pp = t >> 4, d4 = (t & 15) << 2;
    *(float4*)&ps[pp][d4] = *(const float4*)&pq_s[((size_t)bh * NP + pp) * HD + d4];
  }
  __syncthreads();
  const int p = t & 15, ig = t >> 4;
  for (int rep = 0; rep < 4; ++rep) {
    const int i = rep * 16 + ig;
    float acc = 0.f;
    for (int d = 0; d < HD; ++d) acc += qs[i][d] * ps[p][d];
    pe[(size_t)bh * (N_TOK * NP) + (size_t)(i0 + i) * NP + p] = acc;
  }
}

// ---------------- partial column max ----------------
__global__ __launch_bounds__(256) void colmax_part_kernel(
    const float* __restrict__ pe, float* __restrict__ red)
{
  const int seg = blockIdx.x, bh = blockIdx.y;
  const int t = threadIdx.x;
  const int p = t & 15, g = t >> 4;
  __shared__ float rs[16][17];
  const size_t base = (size_t)bh * (N_TOK * NP) + (size_t)seg * 128 * NP;
  float mx = -3.0e38f;
  for (int i = g * 8; i < g * 8 + 8; ++i)
    mx = fmaxf(mx, pe[base + (size_t)i * NP + p]);
  rs[g][p] = mx;
  __syncthreads();
  if (t < 16) {
    float m2 = rs[0][t];
    #pragma unroll
    for (int g2 = 1; g2 < 16; ++g2) m2 = fmaxf(m2, rs[g2][t]);
    red[((size_t)bh * 16 + seg) * 16 + t] = m2;
  }
}

// ---------------- fused exp + per-chunk totals via MFMA ----------------
// Writes e=exp(logit-ms) back into pe; Tk in [p][d] layout, Tv in [d][p] layout.
__global__ __launch_bounds__(256) void totals_mfma_kernel(
    const unsigned short* __restrict__ Kbf, const unsigned short* __restrict__ Vbf,
    float* __restrict__ pe, const float* __restrict__ redm,
    float* __restrict__ Tk, float* __restrict__ Tv, float* __restrict__ Tsc)
{
  const int c = blockIdx.x, bh = blockIdx.y;
  const int ib = bh >> 4, h = bh & 15;
  const int t = threadIdx.x;
  const int i0 = c * CHK;
  const int lane = t & 63, w = t >> 6;
  const int lr = lane & 15, lg = lane >> 4;

  __shared__ unsigned short KT[64][80];   // [d][j]
  __shared__ unsigned short VT[64][80];   // [d][j]
  __shared__ unsigned short EbT[16][80];  // [p][j]
  __shared__ float Ef[64][20];            // [j][p] f32
  __shared__ float ms[16];
  __shared__ float tspart[4][16];

  if (t < 16) {
    float m2 = -3.0e38f;
    #pragma unroll
    for (int s = 0; s < 16; ++s) m2 = fmaxf(m2, redm[((size_t)bh * 16 + s) * 16 + t]);
    ms[t] = m2;
  }
  __syncthreads();

  #pragma unroll
  for (int it = 0; it < 2; ++it) {
    const int task = t + it * 256;
    const int j = task & 63, dg = task >> 6;
    const size_t g = ((size_t)(i0 + j) * BATCH + ib) * EMB + h * HD + dg * 8;
    const uint4 ku = *(const uint4*)&Kbf[g];
    const uint4 vu = *(const uint4*)&Vbf[g];
    const unsigned short* kk = (const unsigned short*)&ku;
    const unsigned short* vv = (const unsigned short*)&vu;
    #pragma unroll
    for (int e = 0; e < 8; ++e) { KT[dg * 8 + e][j] = kk[e]; VT[dg * 8 + e][j] = vv[e]; }
  }
  {
    const int j = t >> 2, p0 = (t & 3) << 2;
    const size_t gi = (size_t)bh * (N_TOK * NP) + (size_t)(i0 + j) * NP + p0;
    float4 l4 = *(const float4*)&pe[gi];
    l4.x = expf(l4.x - ms[p0]);     l4.y = expf(l4.y - ms[p0 + 1]);
    l4.z = expf(l4.z - ms[p0 + 2]); l4.w = expf(l4.w - ms[p0 + 3]);
    *(float4*)&pe[gi] = l4;
    Ef[j][p0] = l4.x; Ef[j][p0 + 1] = l4.y; Ef[j][p0 + 2] = l4.z; Ef[j][p0 + 3] = l4.w;
    EbT[p0][j] = f2bf(l4.x); EbT[p0 + 1][j] = f2bf(l4.y);
    EbT[p0 + 2][j] = f2bf(l4.z); EbT[p0 + 3][j] = f2bf(l4.w);
  }
  __syncthreads();

  if (t < 64) {
    const int p = t & 15, qq = t >> 4;
    float s = 0.f;
    #pragma unroll
    for (int jj = 0; jj < 16; ++jj) s += Ef[qq * 16 + jj][p];
    tspart[qq][p] = s;
  }

  short8 ae0 = *(const short8*)&EbT[lr][lg * 8];
  short8 ae1 = *(const short8*)&EbT[lr][32 + lg * 8];
  const size_t tb = (size_t)(bh * NCHK + c) * 1024;

  {  // Tk_pd: rows p, cols d ; wave w -> col-frag w
    f32x4 ka = {};
    short8 bk0 = *(const short8*)&KT[w * 16 + lr][lg * 8];
    short8 bk1 = *(const short8*)&KT[w * 16 + lr][32 + lg * 8];
    ka = __builtin_amdgcn_mfma_f32_16x16x32_bf16(ae0, bk0, ka, 0, 0, 0);
    ka = __builtin_amdgcn_mfma_f32_16x16x32_bf16(ae1, bk1, ka, 0, 0, 0);
    #pragma unroll
    for (int q = 0; q < 4; ++q) Tk[tb + (lg * 4 + q) * 64 + w * 16 + lr] = ka[q];
  }
  {  // Tv_dp: rows d, cols p ; wave w -> row-strip w
    f32x4 va = {};
    short8 av0 = *(const short8*)&VT[w * 16 + lr][lg * 8];
    short8 av1 = *(const short8*)&VT[w * 16 + lr][32 + lg * 8];
    va = __builtin_amdgcn_mfma_f32_16x16x32_bf16(av0, ae0, va, 0, 0, 0);
    va = __builtin_amdgcn_mfma_f32_16x16x32_bf16(av1, ae1, va, 0, 0, 0);
    #pragma unroll
    for (int q = 0; q < 4; ++q) Tv[tb + (w * 16 + lg * 4 + q) * 16 + lr] = va[q];
  }
  __syncthreads();
  if (t < 16)
    Tsc[(size_t)(bh * NCHK + c) * 16 + t] =
        tspart[0][t] + tspart[1][t] + tspart[2][t] + tspart[3][t];
}

// ---------------- exclusive scan over chunks ----------------
__global__ __launch_bounds__(256) void chunk_scan_kernel(
    float* __restrict__ Tk, float* __restrict__ Tv, float* __restrict__ Ts)
{
  const int bh = blockIdx.x, y = blockIdx.y, t = threadIdx.x;
  const int slot = y * 256 + t;
  float* arr = (slot < 1024) ? Tk : Tv;
  const int e = slot & 1023;
  const size_t base = (size_t)bh * (NCHK * 1024) + e;
  float v[NCHK];
  #pragma unroll
  for (int c = 0; c < NCHK; ++c) v[c] = arr[base + (size_t)c * 1024];
  float run = 0.f;
  #pragma unroll
  for (int c = 0; c < NCHK; ++c) { arr[base + (size_t)c * 1024] = run; run += v[c]; }
  if (y == 7 && t < 16) {
    const size_t sb = (size_t)bh * (NCHK * 16) + t;
    float s[NCHK];
    #pragma unroll
    for (int c = 0; c < NCHK; ++c) s[c] = Ts[sb + c * 16];
    float rs = 0.f;
    #pragma unroll
    for (int c = 0; c < NCHK; ++c) { Ts[sb + c * 16] = rs; rs += s[c]; }
  }
}

// ---------------- within-chunk causal attention via MFMA ----------------
__global__ __launch_bounds__(256) void attn_mfma_kernel(
    const unsigned short* __restrict__ qbf, const unsigned short* __restrict__ Kbf,
    const unsigned short* __restrict__ Vbf, const float* __restrict__ pe,
    const float* __restrict__ Tk, const float* __restrict__ Tv,
    const float* __restrict__ Ts, float* __restrict__ aw_buf,
    unsigned short* __restrict__ outpre)
{
  const int c = blockIdx.x, bh = blockIdx.y;
  const int ib = bh >> 4, h = bh & 15;
  const int t = threadIdx.x;
  const int i0 = c * CHK;
  const int lane = t & 63, w = t >> 6;
  const int ws = w * 16;
  const int lr = lane & 15, lg = lane >> 4;
  const int nsl = (w >> 1) + 1;    // j-slices of 32 this wave needs

  __shared__ unsigned short Qb[64][80];    // [i][d]
  __shared__ unsigned short Kb[64][80];    // [j][d]
  __shared__ unsigned short VT[64][80];    // [d][j]
  __shared__ unsigned short Ab[64][80];    // masked S / B, per-wave strips
  __shared__ unsigned short Eb[64][40];    // [j][p], cols16..31 = 0
  __shared__ unsigned short EbT[16][80];   // [p][j]
  __shared__ unsigned short Nbt[16][80];   // [p][d]
  __shared__ unsigned short Mbt[64][40];   // [d][p], cols16..31 = 0
  __shared__ unsigned short Gb[64][40];    // [i][p], cols16..31 = 0
  __shared__ float Sbf[16];

  #pragma unroll
  for (int it = 0; it < 2; ++it) {
    const int task = t + it * 256;
    const int i = task >> 3, d0 = (task & 7) << 3;
    const size_t g = ((size_t)(i0 + i) * BATCH + ib) * EMB + h * HD + d0;
    *(uint4*)&Qb[i][d0] = *(const uint4*)&qbf[g];
    *(uint4*)&Kb[i][d0] = *(const uint4*)&Kbf[g];
  }
  #pragma unroll
  for (int it = 0; it < 2; ++it) {
    const int task = t + it * 256;
    const int j = task & 63, dg = task >> 6;
    const size_t g = ((size_t)(i0 + j) * BATCH + ib) * EMB + h * HD + dg * 8;
    const uint4 vu = *(const uint4*)&Vbf[g];
    const unsigned short* vv = (const unsigned short*)&vu;
    #pragma unroll
    for (int e = 0; e < 8; ++e) VT[dg * 8 + e][j] = vv[e];
  }
  {
    const int j = t >> 2, p0 = (t & 3) << 2;
    const float4 e4 = *(const float4*)&pe[(size_t)bh * (N_TOK * NP) + (size_t)(i0 + j) * NP + p0];
    const unsigned short b0 = f2bf(e4.x), b1 = f2bf(e4.y), b2 = f2bf(e4.z), b3 = f2bf(e4.w);
    Eb[j][p0] = b0; Eb[j][p0 + 1] = b1; Eb[j][p0 + 2] = b2; Eb[j][p0 + 3] = b3;
    Eb[j][p0 + 16] = 0; Eb[j][p0 + 17] = 0; Eb[j][p0 + 18] = 0; Eb[j][p0 + 19] = 0;
    EbT[p0][j] = b0; EbT[p0 + 1][j] = b1; EbT[p0 + 2][j] = b2; EbT[p0 + 3][j] = b3;
  }
  {
    const int p = t >> 4, d0 = (t & 15) << 2;
    const float4 v = *(const float4*)&Tk[(size_t)(bh * NCHK + c) * 1024 + p * 64 + d0];
    Nbt[p][d0] = f2bf(v.x); Nbt[p][d0 + 1] = f2bf(v.y);
    Nbt[p][d0 + 2] = f2bf(v.z); Nbt[p][d0 + 3] = f2bf(v.w);
  }
  {
    const int d = t >> 2, p0 = (t & 3) << 2;
    const float4 v = *(const float4*)&Tv[(size_t)(bh * NCHK + c) * 1024 + d * 16 + p0];
    Mbt[d][p0] = f2bf(v.x); Mbt[d][p0 + 1] = f2bf(v.y);
    Mbt[d][p0 + 2] = f2bf(v.z); Mbt[d][p0 + 3] = f2bf(v.w);
    Mbt[d][p0 + 16] = 0; Mbt[d][p0 + 17] = 0; Mbt[d][p0 + 18] = 0; Mbt[d][p0 + 19] = 0;
  }
  if (t < 16) Sbf[t] = Ts[(size_t)(bh * NCHK + c) * 16 + t];
  __syncthreads();
  // From here: each wave touches only its own 16-row strip of Ab/Gb -> no more barriers.

  // ---- stage 1: S = Q@K^T (frags 0..w), mask, stage to Ab as bf16
  short8 avq0 = *(const short8*)&Qb[ws + lr][lg * 8];
  short8 avq1 = *(const short8*)&Qb[ws + lr][32 + lg * 8];

  f32x4 sacc[4] = {};
  for (int n = 0; n <= w; ++n) {
    short8 bk0 = *(const short8*)&Kb[n * 16 + lr][lg * 8];
    short8 bk1 = *(const short8*)&Kb[n * 16 + lr][32 + lg * 8];
    sacc[n] = __builtin_amdgcn_mfma_f32_16x16x32_bf16(avq0, bk0, sacc[n], 0, 0, 0);
    sacc[n] = __builtin_amdgcn_mfma_f32_16x16x32_bf16(avq1, bk1, sacc[n], 0, 0, 0);
  }
  #pragma unroll
  for (int q = 0; q < 4; ++q)
    if (lr >= lg * 4 + q) sacc[w][q] = 0.f;    // diag frag: keep strictly j<i
  for (int n = 0; n < 2 * nsl; ++n)
    #pragma unroll
    for (int q = 0; q < 4; ++q)
      Ab[ws + lg * 4 + q][n * 16 + lr] = f2bf(sacc[n][q]);

  // ---- W1 = Q@Nb + S_masked@E ; Sc = Sb + tril_ones@E
  short8 bve0 = *(const short8*)&EbT[lr][lg * 8];
  short8 bve1 = *(const short8*)&EbT[lr][32 + lg * 8];

  f32x4 wacc = {};
  {
    short8 bn0 = *(const short8*)&Nbt[lr][lg * 8];
    short8 bn1 = *(const short8*)&Nbt[lr][32 + lg * 8];
    wacc = __builtin_amdgcn_mfma_f32_16x16x32_bf16(avq0, bn0, wacc, 0, 0, 0);
    wacc = __builtin_amdgcn_mfma_f32_16x16x32_bf16(avq1, bn1, wacc, 0, 0, 0);
  }
  for (int ks = 0; ks < nsl; ++ks) {
    short8 aa = *(const short8*)&Ab[ws + lr][ks * 32 + lg * 8];
    wacc = __builtin_amdgcn_mfma_f32_16x16x32_bf16(aa, ks ? bve1 : bve0, wacc, 0, 0, 0);
  }
  const float s0 = Sbf[lr];
  f32x4 scacc = {s0, s0, s0, s0};
  for (int ks = 0; ks < nsl; ++ks) {
    const int jb = ks * 32 + lg * 8;
    const int irow = ws + lr;
    short8 ones;
    #pragma unroll
    for (int e = 0; e < 8; ++e) ones[e] = (short)((jb + e < irow) ? 0x3F80 : 0);
    scacc = __builtin_amdgcn_mfma_f32_16x16x32_bf16(ones, ks ? bve1 : bve0, scacc, 0, 0, 0);
  }

  // ---- finalize: softmax over p, write aw, stage G
  const size_t awbase = (size_t)bh * (N_TOK * NP) + (size_t)i0 * NP;
  #pragma unroll
  for (int q = 0; q < 4; ++q) {
    const int il = lg * 4 + q;
    const float ssum = scacc[q];
    const float ssafe = (ssum > 0.f) ? ssum : 1.f;
    const float wv = SCALING * wacc[q] / ssafe;
    float m = wv;
    #pragma unroll
    for (int off = 1; off < 16; off <<= 1) m = fmaxf(m, __shfl_xor(m, off, 64));
    const float e = expf(wv - m);
    float ss = e;
    #pragma unroll
    for (int off = 1; off < 16; off <<= 1) ss += __shfl_xor(ss, off, 64);
    const float aw = e / ss;
    aw_buf[awbase + (size_t)(ws + il) * NP + lr] = aw;
    const float g = aw / ssafe;
    Gb[ws + il][lr] = f2bf(g);
    Gb[ws + il][lr + 16] = 0;
  }

  // ---- stage 2: B = G@E^T (frags 0..w), mask, stage; out = G@Mb + B@V
  short8 ga = *(const short8*)&Gb[ws + lr][lg * 8];   // k=p, zero-padded to 32
  f32x4 bacc[4] = {};
  for (int n = 0; n <= w; ++n) {
    short8 be = *(const short8*)&Eb[n * 16 + lr][lg * 8];
    bacc[n] = __builtin_amdgcn_mfma_f32_16x16x32_bf16(ga, be, bacc[n], 0, 0, 0);
  }
  #pragma unroll
  for (int q = 0; q < 4; ++q)
    if (lr >= lg * 4 + q) bacc[w][q] = 0.f;
  for (int n = 0; n < 2 * nsl; ++n)
    #pragma unroll
    for (int q = 0; q < 4; ++q)
      Ab[ws + lg * 4 + q][n * 16 + lr] = f2bf(bacc[n][q]);

  f32x4 oacc[4] = {};
  #pragma unroll
  for (int dn = 0; dn < 4; ++dn) {
    short8 bm = *(const short8*)&Mbt[dn * 16 + lr][lg * 8];
    oacc[dn] = __builtin_amdgcn_mfma_f32_16x16x32_bf16(ga, bm, oacc[dn], 0, 0, 0);
  }
  for (int ks = 0; ks < nsl; ++ks) {
    short8 ab = *(const short8*)&Ab[ws + lr][ks * 32 + lg * 8];
    #pragma unroll
    for (int dn = 0; dn < 4; ++dn) {
      short8 bv = *(const short8*)&VT[dn * 16 + lr][ks * 32 + lg * 8];
      oacc[dn] = __builtin_amdgcn_mfma_f32_16x16x32_bf16(ab, bv, oacc[dn], 0, 0, 0);
    }
  }

  #pragma unroll
  for (int dn = 0; dn < 4; ++dn)
    #pragma unroll
    for (int q = 0; q < 4; ++q) {
      const int i = ws + lg * 4 + q;
      const int d = dn * 16 + lr;
      outpre[((size_t)(i0 + i) * BATCH + ib) * EMB + h * HD + d] = f2bf(oacc[dn][q]);
    }
}

// ---------------- aw mean over heads ----------------
__global__ __launch_bounds__(256) void aw_avg_kernel(
    const float* __restrict__ aw_buf, float* __restrict__ out_aw)
{
  const int idx = blockIdx.x * 256 + threadIdx.x;
  const int p = idx & 15;
  const int i = (idx >> 4) & 2047;
  const int ib = idx >> 15;
  float s = 0.f;
  for (int hh = 0; hh < NH; ++hh)
    s += aw_buf[((size_t)(ib * NH + hh) * N_TOK + i) * NP + p];
  out_aw[idx] = s * (1.f / 16.f);
}

extern "C" void kernel_launch(void* const* d_in, const int* in_sizes, int n_in,
                              void* d_out, int out_size, void* d_ws, size_t ws_size,
                              hipStream_t stream) {
  const float* query  = (const float*)d_in[0];
  const float* pquery = (const float*)d_in[1];
  const float* Wpq    = (const float*)d_in[2];
  const float* bpq    = (const float*)d_in[3];
  const float* Wk     = (const float*)d_in[4];
  const float* bk     = (const float*)d_in[5];
  const float* Wv     = (const float*)d_in[6];
  const float* bv     = (const float*)d_in[7];
  const float* Wo     = (const float*)d_in[8];
  const float* bo     = (const float*)d_in[9];
  float* out = (float*)d_out;
  float* ws  = (float*)d_ws;

  float* pq_s   = ws;                       // 32768
  float* pe     = pq_s + 32768;             // 1048576
  float* aw_buf = pe + 1048576;             // 1048576
  float* Tk     = aw_buf + 1048576;         // 1048576
  float* Tv     = Tk + 1048576;             // 1048576
  float* Ts     = Tv + 1048576;             // 16384
  float* redm   = Ts + 16384;               // 8192
  unsigned short* qbf  = (unsigned short*)(redm + 8192);
  unsigned short* Kbf  = qbf + 4194304;
  unsigned short* Vbf  = Kbf + 4194304;
  unsigned short* wkbf = Vbf + 4194304;
  unsigned short* wvbf = wkbf + 1048576;
  unsigned short* wobf = wvbf + 1048576;
  unsigned short* opbf = wobf + 1048576;

  cvt_bf16_kernel<<<1024, 256, 0, stream>>>(query, qbf, 1048576);
  cvt_bf16_kernel<<<256, 256, 0, stream>>>(Wk, wkbf, 262144);
  cvt_bf16_kernel<<<256, 256, 0, stream>>>(Wv, wvbf, 262144);
  cvt_bf16_kernel<<<256, 256, 0, stream>>>(Wo, wobf, 262144);
  pq_proj_kernel<<<dim3(32, 16), 256, 0, stream>>>(pquery, Wpq, bpq, pq_s);
  mfma_gemm_nt<true><<<dim3(8, 32), 256, 0, stream>>>(qbf, wkbf, bk, Kbf, 4096, 1024, 1024);
  mfma_gemm_nt<true><<<dim3(8, 32), 256, 0, stream>>>(qbf, wvbf, bv, Vbf, 4096, 1024, 1024);
  pattn_kernel<<<dim3(NCHK, BHN), 256, 0, stream>>>(query, pq_s, pe);
  colmax_part_kernel<<<dim3(16, BHN), 256, 0, stream>>>(pe, redm);
  totals_mfma_kernel<<<dim3(NCHK, BHN), 256, 0, stream>>>(Kbf, Vbf, pe, redm, Tk, Tv, Ts);
  chunk_scan_kernel<<<dim3(BHN, 8), 256, 0, stream>>>(Tk, Tv, Ts);
  attn_mfma_kernel<<<dim3(NCHK, BHN), 256, 0, stream>>>(qbf, Kbf, Vbf, pe, Tk, Tv, Ts,
                                                        aw_buf, opbf);
  aw_avg_kernel<<<256, 256, 0, stream>>>(aw_buf, out + 4194304);
  mfma_gemm_nt<false><<<dim3(8, 32), 256, 0, stream>>>(opbf, wobf, bo, out, 4096, 1024, 1024);
}

// Round 5
// 137.084 us; speedup vs baseline: 5.8108x; 1.2498x over previous
//
#include <hip/hip_runtime.h>
#include <cstddef>

#define N_TOK 2048
#define BATCH 2
#define EMB   1024
#define NH    16
#define HD    64
#define NP    16
#define BHN   32
#define CHK   64
#define NCHK  32
#define SCALING 0.125f

typedef __attribute__((ext_vector_type(8))) short short8;
typedef __attribute__((ext_vector_type(4))) float f32x4;

typedef __attribute__((address_space(1))) const void gvoid;
typedef __attribute__((address_space(3))) void lvoid;
__device__ __forceinline__ void gload16(const void* g, void* l) {
  __builtin_amdgcn_global_load_lds((gvoid*)g, (lvoid*)l, 16, 0, 0);
}

__device__ __forceinline__ unsigned short f2bf(float f) {
  unsigned u = __float_as_uint(f);
  u += 0x7FFFu + ((u >> 16) & 1u);
  return (unsigned short)(u >> 16);
}

// ---------------- fused prep: bf16 converts + weight/bias concat ----------------
__global__ __launch_bounds__(256) void prep_kernel(
    const float* __restrict__ query, const float* __restrict__ Wk,
    const float* __restrict__ Wv, const float* __restrict__ Wo,
    const float* __restrict__ bk, const float* __restrict__ bv,
    unsigned short* __restrict__ qbf, unsigned short* __restrict__ wkvbf,
    unsigned short* __restrict__ wobf, float* __restrict__ bkv)
{
  const int tid = blockIdx.x * 256 + threadIdx.x;
  const int NT = gridDim.x * 256;
  for (int i = tid; i < 1835008; i += NT) {
    const float* src; unsigned short* dst; int off;
    if (i < 1048576)      { src = query; dst = qbf;            off = i; }
    else if (i < 1310720) { src = Wk;    dst = wkvbf;          off = i - 1048576; }
    else if (i < 1572864) { src = Wv;    dst = wkvbf + 1048576; off = i - 1310720; }
    else                  { src = Wo;    dst = wobf;           off = i - 1572864; }
    const float4 v = *(const float4*)&src[(size_t)off * 4];
    ushort4 o;
    o.x = f2bf(v.x); o.y = f2bf(v.y); o.z = f2bf(v.z); o.w = f2bf(v.w);
    *(ushort4*)&dst[(size_t)off * 4] = o;
  }
  if (tid < 512) {
    const int j = tid * 4;
    if (j < 1024) *(float4*)&bkv[j] = *(const float4*)&bk[j];
    else          *(float4*)&bkv[j] = *(const float4*)&bv[j - 1024];
  }
}

// ---------------- bf16 MFMA NT GEMM, global_load_lds staging ----------------
// MODE 0: f32 single output (N=1024). MODE 1: bf16 dual output split at col 1024 (N=2048).
template <int MODE>
__global__ __launch_bounds__(256) void mfma_gemm2(
    const unsigned short* __restrict__ Xb, const unsigned short* __restrict__ Wb,
    const float* __restrict__ bias, unsigned short* __restrict__ Y0,
    unsigned short* __restrict__ Y1, float* __restrict__ Yf, int N, int K)
{
  __shared__ unsigned short As[128 * 32];
  __shared__ unsigned short Bs[128 * 32];
  const int t = threadIdx.x;
  const int m0 = blockIdx.y * 128, n0 = blockIdx.x * 128;
  const int lane = t & 63, w = t >> 6, wr = w >> 1, wc = w & 1;
  const int lr = lane & 15, lg = lane >> 4;
  const int srow = t >> 2, scol = (t & 3) << 3;
  f32x4 acc[4][4] = {};

  for (int k0 = 0; k0 < K; k0 += 32) {
    gload16(&Xb[(size_t)(m0 + srow) * K + k0 + scol], &As[t * 8]);
    gload16(&Xb[(size_t)(m0 + srow + 64) * K + k0 + scol], &As[2048 + t * 8]);
    gload16(&Wb[(size_t)(n0 + srow) * K + k0 + scol], &Bs[t * 8]);
    gload16(&Wb[(size_t)(n0 + srow + 64) * K + k0 + scol], &Bs[2048 + t * 8]);
    __syncthreads();
    short8 av[4], bv[4];
    #pragma unroll
    for (int m = 0; m < 4; ++m) av[m] = *(const short8*)&As[(wr * 64 + m * 16 + lr) * 32 + lg * 8];
    #pragma unroll
    for (int n = 0; n < 4; ++n) bv[n] = *(const short8*)&Bs[(wc * 64 + n * 16 + lr) * 32 + lg * 8];
    #pragma unroll
    for (int m = 0; m < 4; ++m)
      #pragma unroll
      for (int n = 0; n < 4; ++n)
        acc[m][n] = __builtin_amdgcn_mfma_f32_16x16x32_bf16(av[m], bv[n], acc[m][n], 0, 0, 0);
    __syncthreads();
  }

  #pragma unroll
  for (int n = 0; n < 4; ++n) {
    const int gcol = n0 + wc * 64 + n * 16 + lr;
    const float bcol = bias[gcol];
    #pragma unroll
    for (int m = 0; m < 4; ++m) {
      const int row0 = m0 + wr * 64 + m * 16 + lg * 4;
      #pragma unroll
      for (int q = 0; q < 4; ++q) {
        const float val = acc[m][n][q] + bcol;
        if (MODE == 0) {
          Yf[(size_t)(row0 + q) * N + gcol] = val;
        } else {
          unsigned short* dst = (n0 < 1024) ? Y0 : Y1;
          dst[(size_t)(row0 + q) * 1024 + (gcol & 1023)] = f2bf(val);
        }
      }
    }
  }
}

// ---------------- pq projection (split-K, 512 blocks) ----------------
__global__ __launch_bounds__(256) void pq_proj_kernel(
    const float* __restrict__ pquery, const float* __restrict__ Wpq,
    const float* __restrict__ bpq, float* __restrict__ pq_s)
{
  const int r = blockIdx.x;
  const int p = r >> 1, ib = r & 1;
  const int seg = blockIdx.y;
  const int t = threadIdx.x;
  const int el = t & 63, ks = t >> 6;
  const int e = seg * 64 + el;
  __shared__ float xs[EMB];
  __shared__ float part[4][64];
  for (int l = t; l < EMB; l += 256) xs[l] = pquery[(size_t)r * EMB + l];
  __syncthreads();
  const float* wrow = &Wpq[(size_t)e * EMB + ks * 256];
  const float* xp = &xs[ks * 256];
  float acc = 0.f;
  #pragma unroll 8
  for (int cc = 0; cc < 256; cc += 4) {
    const float4 w4 = *(const float4*)&wrow[cc];
    acc += xp[cc] * w4.x + xp[cc + 1] * w4.y + xp[cc + 2] * w4.z + xp[cc + 3] * w4.w;
  }
  part[ks][el] = acc;
  __syncthreads();
  if (ks == 0) {
    float s = part[0][el] + part[1][el] + part[2][el] + part[3][el];
    s = (s + bpq[e]) * SCALING;
    const int h = e >> 6, d = e & 63;
    pq_s[((size_t)(ib * NH + h) * NP + p) * HD + d] = s;
  }
}

// ---------------- pattn logits + fused per-chunk column max ----------------
__global__ __launch_bounds__(256) void pattn_kernel(
    const float* __restrict__ query, const float* __restrict__ pq_s,
    float* __restrict__ pe, float* __restrict__ redm)
{
  const int c = blockIdx.x, bh = blockIdx.y;
  const int ib = bh >> 4, h = bh & 15;
  const int t = threadIdx.x;
  const int i0 = c * CHK;
  __shared__ float qs[CHK][68];
  __shared__ float ps[NP][68];
  __shared__ float red[16][17];
  for (int l = t; l < CHK * 16; l += 256) {
    const int i = l >> 4, d4 = (l & 15) << 2;
    *(float4*)&qs[i][d4] =
        *(const float4*)&query[((size_t)(i0 + i) * BATCH + ib) * EMB + h * HD + d4];
  }
  {
    const int pp = t >> 4, d4 = (t & 15) << 2;
    *(float4*)&ps[pp][d4] = *(const float4*)&pq_s[((size_t)bh * NP + pp) * HD + d4];
  }
  __syncthreads();
  const int p = t & 15, ig = t >> 4;
  float mx = -3.0e38f;
  for (int rep = 0; rep < 4; ++rep) {
    const int i = rep * 16 + ig;
    float acc = 0.f;
    for (int d = 0; d < HD; ++d) acc += qs[i][d] * ps[p][d];
    pe[(size_t)bh * (N_TOK * NP) + (size_t)(i0 + i) * NP + p] = acc;
    mx = fmaxf(mx, acc);
  }
  red[ig][p] = mx;
  __syncthreads();
  if (t < 16) {
    float m2 = red[0][t];
    #pragma unroll
    for (int g2 = 1; g2 < 16; ++g2) m2 = fmaxf(m2, red[g2][t]);
    redm[((size_t)bh * NCHK + c) * 16 + t] = m2;
  }
}

// ---------------- fused exp + per-chunk totals via MFMA ----------------
__global__ __launch_bounds__(256) void totals_mfma_kernel(
    const unsigned short* __restrict__ Kbf, const unsigned short* __restrict__ Vbf,
    float* __restrict__ pe, const float* __restrict__ redm,
    float* __restrict__ Tk, float* __restrict__ Tv, float* __restrict__ Tsc)
{
  const int c = blockIdx.x, bh = blockIdx.y;
  const int ib = bh >> 4, h = bh & 15;
  const int t = threadIdx.x;
  const int i0 = c * CHK;
  const int lane = t & 63, w = t >> 6;
  const int lr = lane & 15, lg = lane >> 4;

  __shared__ unsigned short KT[64][80];
  __shared__ unsigned short VT[64][80];
  __shared__ unsigned short EbT[16][80];
  __shared__ float Ef[64][20];
  __shared__ float ms[16];
  __shared__ float tspart[4][16];

  if (t < 16) {
    float m2 = -3.0e38f;
    #pragma unroll
    for (int s = 0; s < NCHK; ++s) m2 = fmaxf(m2, redm[((size_t)bh * NCHK + s) * 16 + t]);
    ms[t] = m2;
  }
  __syncthreads();

  #pragma unroll
  for (int it = 0; it < 2; ++it) {
    const int task = t + it * 256;
    const int j = task & 63, dg = task >> 6;
    const size_t g = ((size_t)(i0 + j) * BATCH + ib) * EMB + h * HD + dg * 8;
    const uint4 ku = *(const uint4*)&Kbf[g];
    const uint4 vu = *(const uint4*)&Vbf[g];
    const unsigned short* kk = (const unsigned short*)&ku;
    const unsigned short* vv = (const unsigned short*)&vu;
    #pragma unroll
    for (int e = 0; e < 8; ++e) { KT[dg * 8 + e][j] = kk[e]; VT[dg * 8 + e][j] = vv[e]; }
  }
  {
    const int j = t >> 2, p0 = (t & 3) << 2;
    const size_t gi = (size_t)bh * (N_TOK * NP) + (size_t)(i0 + j) * NP + p0;
    float4 l4 = *(const float4*)&pe[gi];
    l4.x = expf(l4.x - ms[p0]);     l4.y = expf(l4.y - ms[p0 + 1]);
    l4.z = expf(l4.z - ms[p0 + 2]); l4.w = expf(l4.w - ms[p0 + 3]);
    *(float4*)&pe[gi] = l4;
    Ef[j][p0] = l4.x; Ef[j][p0 + 1] = l4.y; Ef[j][p0 + 2] = l4.z; Ef[j][p0 + 3] = l4.w;
    EbT[p0][j] = f2bf(l4.x); EbT[p0 + 1][j] = f2bf(l4.y);
    EbT[p0 + 2][j] = f2bf(l4.z); EbT[p0 + 3][j] = f2bf(l4.w);
  }
  __syncthreads();

  if (t < 64) {
    const int p = t & 15, qq = t >> 4;
    float s = 0.f;
    #pragma unroll
    for (int jj = 0; jj < 16; ++jj) s += Ef[qq * 16 + jj][p];
    tspart[qq][p] = s;
  }

  short8 ae0 = *(const short8*)&EbT[lr][lg * 8];
  short8 ae1 = *(const short8*)&EbT[lr][32 + lg * 8];
  const size_t tb = (size_t)(bh * NCHK + c) * 1024;

  {
    f32x4 ka = {};
    short8 bk0 = *(const short8*)&KT[w * 16 + lr][lg * 8];
    short8 bk1 = *(const short8*)&KT[w * 16 + lr][32 + lg * 8];
    ka = __builtin_amdgcn_mfma_f32_16x16x32_bf16(ae0, bk0, ka, 0, 0, 0);
    ka = __builtin_amdgcn_mfma_f32_16x16x32_bf16(ae1, bk1, ka, 0, 0, 0);
    #pragma unroll
    for (int q = 0; q < 4; ++q) Tk[tb + (lg * 4 + q) * 64 + w * 16 + lr] = ka[q];
  }
  {
    f32x4 va = {};
    short8 av0 = *(const short8*)&VT[w * 16 + lr][lg * 8];
    short8 av1 = *(const short8*)&VT[w * 16 + lr][32 + lg * 8];
    va = __builtin_amdgcn_mfma_f32_16x16x32_bf16(av0, ae0, va, 0, 0, 0);
    va = __builtin_amdgcn_mfma_f32_16x16x32_bf16(av1, ae1, va, 0, 0, 0);
    #pragma unroll
    for (int q = 0; q < 4; ++q) Tv[tb + (w * 16 + lg * 4 + q) * 16 + lr] = va[q];
  }
  __syncthreads();
  if (t < 16)
    Tsc[(size_t)(bh * NCHK + c) * 16 + t] =
        tspart[0][t] + tspart[1][t] + tspart[2][t] + tspart[3][t];
}

// ---------------- exclusive scan over chunks ----------------
__global__ __launch_bounds__(256) void chunk_scan_kernel(
    float* __restrict__ Tk, float* __restrict__ Tv, float* __restrict__ Ts)
{
  const int bh = blockIdx.x, y = blockIdx.y, t = threadIdx.x;
  const int slot = y * 256 + t;
  float* arr = (slot < 1024) ? Tk : Tv;
  const int e = slot & 1023;
  const size_t base = (size_t)bh * (NCHK * 1024) + e;
  float v[NCHK];
  #pragma unroll
  for (int c = 0; c < NCHK; ++c) v[c] = arr[base + (size_t)c * 1024];
  float run = 0.f;
  #pragma unroll
  for (int c = 0; c < NCHK; ++c) { arr[base + (size_t)c * 1024] = run; run += v[c]; }
  if (y == 7 && t < 16) {
    const size_t sb = (size_t)bh * (NCHK * 16) + t;
    float s[NCHK];
    #pragma unroll
    for (int c = 0; c < NCHK; ++c) s[c] = Ts[sb + c * 16];
    float rs = 0.f;
    #pragma unroll
    for (int c = 0; c < NCHK; ++c) { Ts[sb + c * 16] = rs; rs += s[c]; }
  }
}

// ---------------- within-chunk causal attention via MFMA ----------------
__global__ __launch_bounds__(256) void attn_mfma_kernel(
    const unsigned short* __restrict__ qbf, const unsigned short* __restrict__ Kbf,
    const unsigned short* __restrict__ Vbf, const float* __restrict__ pe,
    const float* __restrict__ Tk, const float* __restrict__ Tv,
    const float* __restrict__ Ts, float* __restrict__ aw_buf,
    unsigned short* __restrict__ outpre)
{
  const int c = blockIdx.x, bh = blockIdx.y;
  const int ib = bh >> 4, h = bh & 15;
  const int t = threadIdx.x;
  const int i0 = c * CHK;
  const int lane = t & 63, w = t >> 6;
  const int ws = w * 16;
  const int lr = lane & 15, lg = lane >> 4;
  const int nsl = (w >> 1) + 1;

  __shared__ unsigned short Qb[64][80];
  __shared__ unsigned short Kb[64][80];
  __shared__ unsigned short VT[64][80];
  __shared__ unsigned short Ab[64][80];
  __shared__ unsigned short Eb[64][40];
  __shared__ unsigned short EbT[16][80];
  __shared__ unsigned short Nbt[16][80];
  __shared__ unsigned short Mbt[64][40];
  __shared__ unsigned short Gb[64][40];
  __shared__ float Sbf[16];

  #pragma unroll
  for (int it = 0; it < 2; ++it) {
    const int task = t + it * 256;
    const int i = task >> 3, d0 = (task & 7) << 3;
    const size_t g = ((size_t)(i0 + i) * BATCH + ib) * EMB + h * HD + d0;
    *(uint4*)&Qb[i][d0] = *(const uint4*)&qbf[g];
    *(uint4*)&Kb[i][d0] = *(const uint4*)&Kbf[g];
  }
  #pragma unroll
  for (int it = 0; it < 2; ++it) {
    const int task = t + it * 256;
    const int j = task & 63, dg = task >> 6;
    const size_t g = ((size_t)(i0 + j) * BATCH + ib) * EMB + h * HD + dg * 8;
    const uint4 vu = *(const uint4*)&Vbf[g];
    const unsigned short* vv = (const unsigned short*)&vu;
    #pragma unroll
    for (int e = 0; e < 8; ++e) VT[dg * 8 + e][j] = vv[e];
  }
  {
    const int j = t >> 2, p0 = (t & 3) << 2;
    const float4 e4 = *(const float4*)&pe[(size_t)bh * (N_TOK * NP) + (size_t)(i0 + j) * NP + p0];
    const unsigned short b0 = f2bf(e4.x), b1 = f2bf(e4.y), b2 = f2bf(e4.z), b3 = f2bf(e4.w);
    Eb[j][p0] = b0; Eb[j][p0 + 1] = b1; Eb[j][p0 + 2] = b2; Eb[j][p0 + 3] = b3;
    Eb[j][p0 + 16] = 0; Eb[j][p0 + 17] = 0; Eb[j][p0 + 18] = 0; Eb[j][p0 + 19] = 0;
    EbT[p0][j] = b0; EbT[p0 + 1][j] = b1; EbT[p0 + 2][j] = b2; EbT[p0 + 3][j] = b3;
  }
  {
    const int p = t >> 4, d0 = (t & 15) << 2;
    const float4 v = *(const float4*)&Tk[(size_t)(bh * NCHK + c) * 1024 + p * 64 + d0];
    Nbt[p][d0] = f2bf(v.x); Nbt[p][d0 + 1] = f2bf(v.y);
    Nbt[p][d0 + 2] = f2bf(v.z); Nbt[p][d0 + 3] = f2bf(v.w);
  }
  {
    const int d = t >> 2, p0 = (t & 3) << 2;
    const float4 v = *(const float4*)&Tv[(size_t)(bh * NCHK + c) * 1024 + d * 16 + p0];
    Mbt[d][p0] = f2bf(v.x); Mbt[d][p0 + 1] = f2bf(v.y);
    Mbt[d][p0 + 2] = f2bf(v.z); Mbt[d][p0 + 3] = f2bf(v.w);
    Mbt[d][p0 + 16] = 0; Mbt[d][p0 + 17] = 0; Mbt[d][p0 + 18] = 0; Mbt[d][p0 + 19] = 0;
  }
  if (t < 16) Sbf[t] = Ts[(size_t)(bh * NCHK + c) * 16 + t];
  __syncthreads();

  short8 avq0 = *(const short8*)&Qb[ws + lr][lg * 8];
  short8 avq1 = *(const short8*)&Qb[ws + lr][32 + lg * 8];

  f32x4 sacc[4] = {};
  for (int n = 0; n <= w; ++n) {
    short8 bk0 = *(const short8*)&Kb[n * 16 + lr][lg * 8];
    short8 bk1 = *(const short8*)&Kb[n * 16 + lr][32 + lg * 8];
    sacc[n] = __builtin_amdgcn_mfma_f32_16x16x32_bf16(avq0, bk0, sacc[n], 0, 0, 0);
    sacc[n] = __builtin_amdgcn_mfma_f32_16x16x32_bf16(avq1, bk1, sacc[n], 0, 0, 0);
  }
  #pragma unroll
  for (int q = 0; q < 4; ++q)
    if (lr >= lg * 4 + q) sacc[w][q] = 0.f;
  for (int n = 0; n < 2 * nsl; ++n)
    #pragma unroll
    for (int q = 0; q < 4; ++q)
      Ab[ws + lg * 4 + q][n * 16 + lr] = f2bf(sacc[n][q]);

  short8 bve0 = *(const short8*)&EbT[lr][lg * 8];
  short8 bve1 = *(const short8*)&EbT[lr][32 + lg * 8];

  f32x4 wacc = {};
  {
    short8 bn0 = *(const short8*)&Nbt[lr][lg * 8];
    short8 bn1 = *(const short8*)&Nbt[lr][32 + lg * 8];
    wacc = __builtin_amdgcn_mfma_f32_16x16x32_bf16(avq0, bn0, wacc, 0, 0, 0);
    wacc = __builtin_amdgcn_mfma_f32_16x16x32_bf16(avq1, bn1, wacc, 0, 0, 0);
  }
  for (int ks = 0; ks < nsl; ++ks) {
    short8 aa = *(const short8*)&Ab[ws + lr][ks * 32 + lg * 8];
    wacc = __builtin_amdgcn_mfma_f32_16x16x32_bf16(aa, ks ? bve1 : bve0, wacc, 0, 0, 0);
  }
  const float s0 = Sbf[lr];
  f32x4 scacc = {s0, s0, s0, s0};
  for (int ks = 0; ks < nsl; ++ks) {
    const int jb = ks * 32 + lg * 8;
    const int irow = ws + lr;
    short8 ones;
    #pragma unroll
    for (int e = 0; e < 8; ++e) ones[e] = (short)((jb + e < irow) ? 0x3F80 : 0);
    scacc = __builtin_amdgcn_mfma_f32_16x16x32_bf16(ones, ks ? bve1 : bve0, scacc, 0, 0, 0);
  }

  const size_t awbase = (size_t)bh * (N_TOK * NP) + (size_t)i0 * NP;
  #pragma unroll
  for (int q = 0; q < 4; ++q) {
    const int il = lg * 4 + q;
    const float ssum = scacc[q];
    const float ssafe = (ssum > 0.f) ? ssum : 1.f;
    const float wv = SCALING * wacc[q] / ssafe;
    float m = wv;
    #pragma unroll
    for (int off = 1; off < 16; off <<= 1) m = fmaxf(m, __shfl_xor(m, off, 64));
    const float e = expf(wv - m);
    float ss = e;
    #pragma unroll
    for (int off = 1; off < 16; off <<= 1) ss += __shfl_xor(ss, off, 64);
    const float aw = e / ss;
    aw_buf[awbase + (size_t)(ws + il) * NP + lr] = aw;
    const float g = aw / ssafe;
    Gb[ws + il][lr] = f2bf(g);
    Gb[ws + il][lr + 16] = 0;
  }

  short8 ga = *(const short8*)&Gb[ws + lr][lg * 8];
  f32x4 bacc[4] = {};
  for (int n = 0; n <= w; ++n) {
    short8 be = *(const short8*)&Eb[n * 16 + lr][lg * 8];
    bacc[n] = __builtin_amdgcn_mfma_f32_16x16x32_bf16(ga, be, bacc[n], 0, 0, 0);
  }
  #pragma unroll
  for (int q = 0; q < 4; ++q)
    if (lr >= lg * 4 + q) bacc[w][q] = 0.f;
  for (int n = 0; n < 2 * nsl; ++n)
    #pragma unroll
    for (int q = 0; q < 4; ++q)
      Ab[ws + lg * 4 + q][n * 16 + lr] = f2bf(bacc[n][q]);

  f32x4 oacc[4] = {};
  #pragma unroll
  for (int dn = 0; dn < 4; ++dn) {
    short8 bm = *(const short8*)&Mbt[dn * 16 + lr][lg * 8];
    oacc[dn] = __builtin_amdgcn_mfma_f32_16x16x32_bf16(ga, bm, oacc[dn], 0, 0, 0);
  }
  for (int ks = 0; ks < nsl; ++ks) {
    short8 ab = *(const short8*)&Ab[ws + lr][ks * 32 + lg * 8];
    #pragma unroll
    for (int dn = 0; dn < 4; ++dn) {
      short8 bv = *(const short8*)&VT[dn * 16 + lr][ks * 32 + lg * 8];
      oacc[dn] = __builtin_amdgcn_mfma_f32_16x16x32_bf16(ab, bv, oacc[dn], 0, 0, 0);
    }
  }

  #pragma unroll
  for (int dn = 0; dn < 4; ++dn)
    #pragma unroll
    for (int q = 0; q < 4; ++q) {
      const int i = ws + lg * 4 + q;
      const int d = dn * 16 + lr;
      outpre[((size_t)(i0 + i) * BATCH + ib) * EMB + h * HD + d] = f2bf(oacc[dn][q]);
    }
}

// ---------------- aw mean over heads ----------------
__global__ __launch_bounds__(256) void aw_avg_kernel(
    const float* __restrict__ aw_buf, float* __restrict__ out_aw)
{
  const int idx = blockIdx.x * 256 + threadIdx.x;
  const int p = idx & 15;
  const int i = (idx >> 4) & 2047;
  const int ib = idx >> 15;
  float s = 0.f;
  for (int hh = 0; hh < NH; ++hh)
    s += aw_buf[((size_t)(ib * NH + hh) * N_TOK + i) * NP + p];
  out_aw[idx] = s * (1.f / 16.f);
}

extern "C" void kernel_launch(void* const* d_in, const int* in_sizes, int n_in,
                              void* d_out, int out_size, void* d_ws, size_t ws_size,
                              hipStream_t stream) {
  const float* query  = (const float*)d_in[0];
  const float* pquery = (const float*)d_in[1];
  const float* Wpq    = (const float*)d_in[2];
  const float* bpq    = (const float*)d_in[3];
  const float* Wk     = (const float*)d_in[4];
  const float* bk     = (const float*)d_in[5];
  const float* Wv     = (const float*)d_in[6];
  const float* bv     = (const float*)d_in[7];
  const float* Wo     = (const float*)d_in[8];
  const float* bo     = (const float*)d_in[9];
  float* out = (float*)d_out;
  float* ws  = (float*)d_ws;

  float* pq_s   = ws;                       // 32768
  float* pe     = pq_s + 32768;             // 1048576
  float* aw_buf = pe + 1048576;             // 1048576
  float* Tk     = aw_buf + 1048576;         // 1048576
  float* Tv     = Tk + 1048576;             // 1048576
  float* Ts     = Tv + 1048576;             // 16384
  float* redm   = Ts + 16384;               // 32*32*16 = 16384
  float* bkv    = redm + 16384;             // 2048
  unsigned short* qbf   = (unsigned short*)(bkv + 2048);
  unsigned short* Kbf   = qbf + 4194304;
  unsigned short* Vbf   = Kbf + 4194304;
  unsigned short* wkvbf = Vbf + 4194304;    // 2097152
  unsigned short* wobf  = wkvbf + 2097152;  // 1048576
  unsigned short* opbf  = wobf + 1048576;   // 4194304

  prep_kernel<<<1024, 256, 0, stream>>>(query, Wk, Wv, Wo, bk, bv, qbf, wkvbf, wobf, bkv);
  pq_proj_kernel<<<dim3(32, 16), 256, 0, stream>>>(pquery, Wpq, bpq, pq_s);
  mfma_gemm2<1><<<dim3(16, 32), 256, 0, stream>>>(qbf, wkvbf, bkv, Kbf, Vbf, nullptr, 2048, 1024);
  pattn_kernel<<<dim3(NCHK, BHN), 256, 0, stream>>>(query, pq_s, pe, redm);
  totals_mfma_kernel<<<dim3(NCHK, BHN), 256, 0, stream>>>(Kbf, Vbf, pe, redm, Tk, Tv, Ts);
  chunk_scan_kernel<<<dim3(BHN, 8), 256, 0, stream>>>(Tk, Tv, Ts);
  attn_mfma_kernel<<<dim3(NCHK, BHN), 256, 0, stream>>>(qbf, Kbf, Vbf, pe, Tk, Tv, Ts,
                                                        aw_buf, opbf);
  aw_avg_kernel<<<256, 256, 0, stream>>>(aw_buf, out + 4194304);
  mfma_gemm2<0><<<dim3(8, 32), 256, 0, stream>>>(opbf, wobf, bo, nullptr, nullptr, out, 1024, 1024);
}